// Round 7
// baseline (415.856 us; speedup 1.0000x reference)
//
#include <hip/hip_runtime.h>
#include <hip/hip_fp16.h>
#include <math.h>

namespace {

constexpr int NN = 100000;   // nodes
constexpr int NE = 1000000;  // edges
constexpr int D  = 64;       // feature dim

constexpr int SB  = 256;                       // rows per scan block
constexpr int NSB = (NN + SB - 1) / SB;        // 391
constexpr int EPB = 1024;                      // edges per block (hist/scatter)
constexpr int NEB = (NE + EPB - 1) / EPB;      // 977
constexpr int SUMW = 1024;                     // summary partial waves

using ushort_t = unsigned short;
typedef __attribute__((ext_vector_type(8))) short short8;  // 8 bf16 (4 VGPRs)
typedef __attribute__((ext_vector_type(4))) float f32x4;   // MFMA 16x16 accumulator

union FragU { uint4 v; short8 s; };

// split two fp32 into packed bf16 hi parts and packed bf16 lo (residual) parts.
__device__ inline void split2(float f0, float f1, unsigned int& hi, unsigned int& lo) {
    unsigned int u0 = __float_as_uint(f0);
    unsigned int u1 = __float_as_uint(f1);
    hi = (u0 >> 16) | (u1 & 0xffff0000u);
    float l0 = f0 - __uint_as_float(u0 & 0xffff0000u);
    float l1 = f1 - __uint_as_float(u1 & 0xffff0000u);
    lo = (__float_as_uint(l0) >> 16) | (__float_as_uint(l1) & 0xffff0000u);
}

__device__ inline unsigned int packh(float a, float b) {   // 2x fp16 (RNE) packed
    union { __half2 h; unsigned int u; } cv;
    cv.h = __float22half2_rn(make_float2(a, b));
    return cv.u;
}

__device__ inline float2 h2f(unsigned int v) {
    union { unsigned int u; __half2 h; } cv;
    cv.u = v;
    return __half22float2(cv.h);
}

// Pass 1: degree histogram (1M global atomics on L2-resident 400KB counters).
// Block NEB additionally builds the MFMA A-operand fragments for W1|W2
// (bf16 hi/lo), layout per matrix: [ftile(4)][ktile(2)][hi/lo(2)][lane(64)];
// lane l holds A[m][k], m = ft*16 + (l&15), k = kt*32 + (l>>4)*8 + j.
__global__ void hist_k(const int* __restrict__ rows, int* __restrict__ deg, int e,
                       const float* __restrict__ W1, const float* __restrict__ W2,
                       uint4* __restrict__ fb) {
    if (blockIdx.x == NEB) {
        int lane = threadIdx.x;
        if (lane < 64) {
            for (int w = 0; w < 2; ++w) {
                const float* W = (w != 0) ? W2 : W1;
                uint4* out = fb + w * 1024;
                for (int ft = 0; ft < 4; ++ft) {
                    for (int kt = 0; kt < 2; ++kt) {
                        int m  = ft * 16 + (lane & 15);
                        int k0 = kt * 32 + (lane >> 4) * 8;
                        unsigned int hi0, lo0, hi1, lo1, hi2, lo2, hi3, lo3;
                        split2(W[(k0 + 0) * 64 + m], W[(k0 + 1) * 64 + m], hi0, lo0);
                        split2(W[(k0 + 2) * 64 + m], W[(k0 + 3) * 64 + m], hi1, lo1);
                        split2(W[(k0 + 4) * 64 + m], W[(k0 + 5) * 64 + m], hi2, lo2);
                        split2(W[(k0 + 6) * 64 + m], W[(k0 + 7) * 64 + m], hi3, lo3);
                        out[((ft * 2 + kt) * 2 + 0) * 64 + lane] = make_uint4(hi0, hi1, hi2, hi3);
                        out[((ft * 2 + kt) * 2 + 1) * 64 + lane] = make_uint4(lo0, lo1, lo2, lo3);
                    }
                }
            }
        }
        return;
    }
    int base = blockIdx.x * EPB + threadIdx.x;
#pragma unroll
    for (int j = 0; j < 4; ++j) {
        int i = base + j * 256;
        if (i < e) {
            atomicAdd(&deg[rows[i]], 1);
        }
    }
}

// Pass 2a: per-block partial sums of deg (391 x 256)
__global__ void scan1_k(const int* __restrict__ deg, int* __restrict__ part) {
    __shared__ int red[4];
    int b = blockIdx.x;
    int t = threadIdx.x;
    int lane = t & 63;
    int wid = t >> 6;
    int i = b * SB + t;
    int v = (i < NN) ? deg[i] : 0;
#pragma unroll
    for (int off = 1; off < 64; off <<= 1) {
        v += __shfl_xor(v, off, 64);
    }
    if (lane == 0) red[wid] = v;
    __syncthreads();
    if (t == 0) {
        part[b] = red[0] + red[1] + red[2] + red[3];
    }
}

// Pass 2b: exclusive scan of the 391 partials (single 512-thread block)
__global__ void scan2_k(int* __restrict__ part) {
    __shared__ int sm[512];
    int t = threadIdx.x;
    int v = (t < NSB) ? part[t] : 0;
    sm[t] = v;
    __syncthreads();
    for (int off = 1; off < 512; off <<= 1) {
        int u = (t >= off) ? sm[t - off] : 0;
        __syncthreads();
        sm[t] += u;
        __syncthreads();
    }
    if (t < NSB) {
        part[t] = sm[t] - v;  // exclusive
    }
}

// Pass 2c: rowstart = global exclusive scan; cur = copy; dis = rsqrt(deg+1)
__global__ void scan3_k(const int* __restrict__ deg, const int* __restrict__ part,
                        int* __restrict__ rowstart, int* __restrict__ cur,
                        float* __restrict__ dis) {
    __shared__ int wsum[4];
    int b = blockIdx.x;
    int t = threadIdx.x;
    int lane = t & 63;
    int wid = t >> 6;
    int i = b * SB + t;
    int d = (i < NN) ? deg[i] : 0;
    int inc = d;
#pragma unroll
    for (int off = 1; off < 64; off <<= 1) {
        int u = __shfl_up(inc, off);
        if (lane >= off) inc += u;
    }
    if (lane == 63) wsum[wid] = inc;
    __syncthreads();
    int wpre = 0;
    for (int w = 0; w < wid; ++w) wpre += wsum[w];
    int rs = part[b] + wpre + inc - d;
    if (i < NN) {
        rowstart[i] = rs;
        cur[i] = rs;
        dis[i] = rsqrtf((float)(d + 1));  // +1 self-loop
    }
}

// Pass 3: CSR scatter. pos = atomicAdd(cur[r]); scols[pos] = c.
// Neighbor order within a row is nondeterministic -- fine for a sum.
__global__ void scatter_k(const int* __restrict__ rows, const int* __restrict__ cols,
                          int* __restrict__ cur, int* __restrict__ scols, int e) {
    int base = blockIdx.x * EPB + threadIdx.x;
#pragma unroll
    for (int j = 0; j < 4; ++j) {
        int i = base + j * 256;
        if (i < e) {
            int r = rows[i];
            int c = cols[i];
            int pos = atomicAdd(&cur[r], 1);
            scols[pos] = c;
        }
    }
}

// Layer-1 MFMA GEMM: per output row c computes BOTH products
//   P[c] = dis[c]*(x[c]@W1),  N[c] = dis[c]*(x[perm[c]]@W1)
// via mfma_f32_16x16x32_bf16 with bf16 hi/lo split (~fp32 accuracy).
// One wave per 16-row tile; dense 256B interleaved-row writes (no scatter).
__global__ void gemm1_k(const float* __restrict__ in, const uint4* __restrict__ wf,
                        ushort_t* __restrict__ tPN, const int* __restrict__ perm,
                        const float* __restrict__ dis, int n) {
    int lane  = threadIdx.x & 63;
    int wtile = (int)((blockIdx.x * blockDim.x + threadIdx.x) >> 6);
    if (wtile * 16 >= n) return;
    int node = wtile * 16 + (lane & 15);
    int kg   = lane >> 4;  // 0..3

    FragU whi[4][2];
    FragU wlo[4][2];
#pragma unroll
    for (int ft = 0; ft < 4; ++ft) {
#pragma unroll
        for (int kt = 0; kt < 2; ++kt) {
            whi[ft][kt].v = wf[((ft * 2 + kt) * 2 + 0) * 64 + lane];
            wlo[ft][kt].v = wf[((ft * 2 + kt) * 2 + 1) * 64 + lane];
        }
    }

    const float4* xr = (const float4*)in;
    size_t rbase = (size_t)node * 16 + (size_t)(kg * 2);
    int pnode = perm[node];
    size_t pbase = (size_t)pnode * 16 + (size_t)(kg * 2);
    f32x4 accP[4];
    f32x4 accN[4];
#pragma unroll
    for (int ft = 0; ft < 4; ++ft) {
        accP[ft] = f32x4{0.f, 0.f, 0.f, 0.f};
        accN[ft] = f32x4{0.f, 0.f, 0.f, 0.f};
    }
#pragma unroll
    for (int kt = 0; kt < 2; ++kt) {
        float4 a0 = xr[rbase + kt * 8];
        float4 a1 = xr[rbase + kt * 8 + 1];
        float4 g0 = xr[pbase + kt * 8];
        float4 g1 = xr[pbase + kt * 8 + 1];
        unsigned int h0, l0, h1, l1, h2, l2, h3, l3;
        split2(a0.x, a0.y, h0, l0);
        split2(a0.z, a0.w, h1, l1);
        split2(a1.x, a1.y, h2, l2);
        split2(a1.z, a1.w, h3, l3);
        FragU xhiP, xloP;
        xhiP.v = make_uint4(h0, h1, h2, h3);
        xloP.v = make_uint4(l0, l1, l2, l3);
        split2(g0.x, g0.y, h0, l0);
        split2(g0.z, g0.w, h1, l1);
        split2(g1.x, g1.y, h2, l2);
        split2(g1.z, g1.w, h3, l3);
        FragU xhiN, xloN;
        xhiN.v = make_uint4(h0, h1, h2, h3);
        xloN.v = make_uint4(l0, l1, l2, l3);
#pragma unroll
        for (int ft = 0; ft < 4; ++ft) {
            accP[ft] = __builtin_amdgcn_mfma_f32_16x16x32_bf16(whi[ft][kt].s, xhiP.s, accP[ft], 0, 0, 0);
            accP[ft] = __builtin_amdgcn_mfma_f32_16x16x32_bf16(whi[ft][kt].s, xloP.s, accP[ft], 0, 0, 0);
            accP[ft] = __builtin_amdgcn_mfma_f32_16x16x32_bf16(wlo[ft][kt].s, xhiP.s, accP[ft], 0, 0, 0);
            accN[ft] = __builtin_amdgcn_mfma_f32_16x16x32_bf16(whi[ft][kt].s, xhiN.s, accN[ft], 0, 0, 0);
            accN[ft] = __builtin_amdgcn_mfma_f32_16x16x32_bf16(whi[ft][kt].s, xloN.s, accN[ft], 0, 0, 0);
            accN[ft] = __builtin_amdgcn_mfma_f32_16x16x32_bf16(wlo[ft][kt].s, xhiN.s, accN[ft], 0, 0, 0);
        }
    }
    int fo = kg * 4;
    float s = dis[node];
    ushort_t* p = tPN + (size_t)node * 128;
#pragma unroll
    for (int ft = 0; ft < 4; ++ft) {
        uint2 up = make_uint2(packh(s * accP[ft][0], s * accP[ft][1]),
                              packh(s * accP[ft][2], s * accP[ft][3]));
        *(uint2*)(p + ft * 16 + fo) = up;
        uint2 un = make_uint2(packh(s * accN[ft][0], s * accN[ft][1]),
                              packh(s * accN[ft][2], s * accN[ft][3]));
        *(uint2*)(p + 64 + ft * 16 + fo) = un;
    }
}

// FUSED layer-1 aggregate + layer-2 GEMM. One block (4 waves) owns 16 rows.
// Phase 1 (gather, R2-proven structure): each wave aggregates 4 rows
// sequentially; lanes 0-31 = P half, 32-63 = N half, 2 feats/lane/4B-load;
// scols reads wave-uniform (scalar). H row (post bias+PReLU) parked in LDS
// [half][16][68] fp32. Phase 2 (MFMA): waves 0,1 -> P, waves 2,3 -> N;
// 2 ftiles/wave; same split2 hi/lo math as gemm1; epilogue scales by
// dis[row], writes fp16 table tOut (dense 8B stores).
__global__ void agg_gemm_k(const ushort_t* __restrict__ tIn, ushort_t* __restrict__ tOut,
                           const float* __restrict__ dis,
                           const int* __restrict__ rowstart, const int* __restrict__ deg,
                           const int* __restrict__ scols,
                           const float* __restrict__ bias, const float* __restrict__ prelu_a,
                           const uint4* __restrict__ wf) {
    __shared__ float Hs[2][16][68];
    int tid = threadIdx.x;
    int lane = tid & 63;
    int wv = tid >> 6;                 // 0..3
    int row0 = blockIdx.x * 16;
    int hl = lane & 31;
    int half = lane >> 5;
    size_t lofs = (size_t)(half * 64 + hl * 2);
    float aPr = *prelu_a;

    for (int rr = 0; rr < 4; ++rr) {
        int r = row0 + wv * 4 + rr;
        int rs   = __builtin_amdgcn_readfirstlane(r);
        int base = __builtin_amdgcn_readfirstlane(rowstart[rs]);
        int dg   = __builtin_amdgcn_readfirstlane(deg[rs]);
        float dr = dis[rs];
        unsigned int sv = *(const unsigned int*)(tIn + (size_t)rs * 128 + lofs);
        float2 fs = h2f(sv);
        float a0 = fs.x;
        float a1 = fs.y;     // self-loop term
        int j = 0;
        for (; j + 4 <= dg; j += 4) {
            int c0 = scols[base + j];
            int c1 = scols[base + j + 1];
            int c2 = scols[base + j + 2];
            int c3 = scols[base + j + 3];
            unsigned int v0 = *(const unsigned int*)(tIn + (size_t)c0 * 128 + lofs);
            unsigned int v1 = *(const unsigned int*)(tIn + (size_t)c1 * 128 + lofs);
            unsigned int v2 = *(const unsigned int*)(tIn + (size_t)c2 * 128 + lofs);
            unsigned int v3 = *(const unsigned int*)(tIn + (size_t)c3 * 128 + lofs);
            float2 f0 = h2f(v0);
            float2 f1 = h2f(v1);
            float2 f2 = h2f(v2);
            float2 f3 = h2f(v3);
            a0 += f0.x + f1.x + f2.x + f3.x;
            a1 += f0.y + f1.y + f2.y + f3.y;
        }
        for (; j < dg; ++j) {
            int c = scols[base + j];
            unsigned int v = *(const unsigned int*)(tIn + (size_t)c * 128 + lofs);
            float2 f = h2f(v);
            a0 += f.x;
            a1 += f.y;
        }
        float2 bv = *(const float2*)(bias + 2 * hl);
        float v0 = fmaf(dr, a0, bv.x);
        float v1 = fmaf(dr, a1, bv.y);
        v0 = v0 >= 0.f ? v0 : aPr * v0;
        v1 = v1 >= 0.f ? v1 : aPr * v1;
        int rl = wv * 4 + rr;
        Hs[half][rl][2 * hl]     = v0;
        Hs[half][rl][2 * hl + 1] = v1;
    }
    __syncthreads();

    // layer-2: out[row] = dis[row] * (H[row] @ W2), per half
    int kg = lane >> 4;
    int nd = lane & 15;
    int hsel = wv >> 1;                // waves 0,1 -> P; 2,3 -> N
    int ftb = (wv & 1) * 2;            // ftiles {0,1} or {2,3}
    FragU whi[2][2];
    FragU wlo[2][2];
#pragma unroll
    for (int f2 = 0; f2 < 2; ++f2) {
#pragma unroll
        for (int kt = 0; kt < 2; ++kt) {
            whi[f2][kt].v = wf[(((ftb + f2) * 2 + kt) * 2 + 0) * 64 + lane];
            wlo[f2][kt].v = wf[(((ftb + f2) * 2 + kt) * 2 + 1) * 64 + lane];
        }
    }
    f32x4 acc[2];
    acc[0] = f32x4{0.f, 0.f, 0.f, 0.f};
    acc[1] = f32x4{0.f, 0.f, 0.f, 0.f};
#pragma unroll
    for (int kt = 0; kt < 2; ++kt) {
        float4 a0 = *(const float4*)&Hs[hsel][nd][kt * 32 + kg * 8];
        float4 a1 = *(const float4*)&Hs[hsel][nd][kt * 32 + kg * 8 + 4];
        unsigned int h0, l0, h1, l1, h2, l2, h3, l3;
        split2(a0.x, a0.y, h0, l0);
        split2(a0.z, a0.w, h1, l1);
        split2(a1.x, a1.y, h2, l2);
        split2(a1.z, a1.w, h3, l3);
        FragU xhi, xlo;
        xhi.v = make_uint4(h0, h1, h2, h3);
        xlo.v = make_uint4(l0, l1, l2, l3);
#pragma unroll
        for (int f2 = 0; f2 < 2; ++f2) {
            acc[f2] = __builtin_amdgcn_mfma_f32_16x16x32_bf16(whi[f2][kt].s, xhi.s, acc[f2], 0, 0, 0);
            acc[f2] = __builtin_amdgcn_mfma_f32_16x16x32_bf16(whi[f2][kt].s, xlo.s, acc[f2], 0, 0, 0);
            acc[f2] = __builtin_amdgcn_mfma_f32_16x16x32_bf16(wlo[f2][kt].s, xhi.s, acc[f2], 0, 0, 0);
        }
    }
    float s = dis[row0 + nd];
    ushort_t* p = tOut + (size_t)(row0 + nd) * 128 + hsel * 64;
    int fo = kg * 4;
#pragma unroll
    for (int f2 = 0; f2 < 2; ++f2) {
        uint2 u = make_uint2(packh(s * acc[f2][0], s * acc[f2][1]),
                             packh(s * acc[f2][2], s * acc[f2][3]));
        *(uint2*)(p + (ftb + f2) * 16 + fo) = u;
    }
}

// Dual gather-aggregate over the interleaved fp16 table (final layer).
// One wave per row; lanes 0-31 = P half, 32-63 = N half; 2 feats/lane.
// outX[r] = dis[r]*(sum_j tX[c_j] + tX[r]) + b
__global__ void agg_dual_k(const ushort_t* __restrict__ tPN,
                           float* __restrict__ dstP, float* __restrict__ dstN,
                           const float* __restrict__ dis,
                           const int* __restrict__ rowstart, const int* __restrict__ deg,
                           const int* __restrict__ scols,
                           const float* __restrict__ bias, int n) {
    int lane = threadIdx.x & 63;
    int hl = lane & 31;
    int half = lane >> 5;
    int r = blockIdx.x * (blockDim.x >> 6) + (threadIdx.x >> 6);
    if (r >= n) return;
    int rs   = __builtin_amdgcn_readfirstlane(r);
    int base = __builtin_amdgcn_readfirstlane(rowstart[rs]);
    int dg   = __builtin_amdgcn_readfirstlane(deg[rs]);
    float dr = dis[rs];
    size_t lofs = (size_t)(half * 64 + hl * 2);
    unsigned int sv = *(const unsigned int*)(tPN + (size_t)rs * 128 + lofs);
    float2 fs = h2f(sv);
    float a0 = fs.x;
    float a1 = fs.y;     // self-loop term
    int j = 0;
    for (; j + 4 <= dg; j += 4) {
        int c0 = scols[base + j];
        int c1 = scols[base + j + 1];
        int c2 = scols[base + j + 2];
        int c3 = scols[base + j + 3];
        unsigned int v0 = *(const unsigned int*)(tPN + (size_t)c0 * 128 + lofs);
        unsigned int v1 = *(const unsigned int*)(tPN + (size_t)c1 * 128 + lofs);
        unsigned int v2 = *(const unsigned int*)(tPN + (size_t)c2 * 128 + lofs);
        unsigned int v3 = *(const unsigned int*)(tPN + (size_t)c3 * 128 + lofs);
        float2 f0 = h2f(v0);
        float2 f1 = h2f(v1);
        float2 f2 = h2f(v2);
        float2 f3 = h2f(v3);
        a0 += f0.x + f1.x + f2.x + f3.x;
        a1 += f0.y + f1.y + f2.y + f3.y;
    }
    for (; j < dg; ++j) {
        int c = scols[base + j];
        unsigned int v = *(const unsigned int*)(tPN + (size_t)c * 128 + lofs);
        float2 f = h2f(v);
        a0 += f.x;
        a1 += f.y;
    }
    float2 bv = *(const float2*)(bias + 2 * hl);
    float v0 = fmaf(dr, a0, bv.x);
    float v1 = fmaf(dr, a1, bv.y);
    float* dst = half ? dstN : dstP;
    *(float2*)(dst + (size_t)rs * D + 2 * hl) = float2{v0, v1};
}

// atomic-free summary: per-wave partial sums into part[wave][64]
__global__ void summary_partial_k(const float* __restrict__ pos, float* __restrict__ part, int n) {
    int lane = threadIdx.x & 63;
    int wave = (blockIdx.x * blockDim.x + threadIdx.x) >> 6;
    int nw = (gridDim.x * blockDim.x) >> 6;
    float s = 0.f;
    for (int r = wave; r < n; r += nw) {
        s += pos[(size_t)r * D + lane];
    }
    part[(size_t)wave * D + lane] = s;
}

// 256 threads: 4-way split over the SUMW partials + LDS reduce (was 1 wave
// reading 256KB serially -- R5 regression)
__global__ void summary_final_k(const float* __restrict__ part, float* __restrict__ out, int n) {
    __shared__ float red[4][64];
    int f = threadIdx.x & 63;
    int g = threadIdx.x >> 6;
    float s = 0.f;
    for (int w = g; w < SUMW; w += 4) {
        s += part[(size_t)w * D + f];
    }
    red[g][f] = s;
    __syncthreads();
    if (threadIdx.x < 64) {
        float m = (red[0][f] + red[1][f] + red[2][f] + red[3][f]) / (float)n;
        out[f] = 1.f / (1.f + expf(-m));
    }
}

} // namespace

extern "C" void kernel_launch(void* const* d_in, const int* in_sizes, int n_in,
                              void* d_out, int out_size, void* d_ws, size_t ws_size,
                              hipStream_t stream) {
    (void)in_sizes; (void)n_in; (void)out_size; (void)ws_size;
    const float* x       = (const float*)d_in[0];
    const int*   ei      = (const int*)  d_in[1];
    const int*   perm    = (const int*)  d_in[2];
    const float* W1      = (const float*)d_in[3];
    const float* b1      = (const float*)d_in[4];
    const float* prelu_a = (const float*)d_in[5];
    const float* W2      = (const float*)d_in[6];
    const float* b2      = (const float*)d_in[7];

    float* outP = (float*)d_out;
    float* outN = outP + (size_t)NN * D;
    float* outS = outN + (size_t)NN * D;

    const int* erows = ei;
    const int* ecols = ei + NE;

    char* ws = (char*)d_ws;
    size_t off = 0;
    auto alloc = [&](size_t bytes) {
        void* p = ws + off;
        off = (off + bytes + 255) & ~(size_t)255;
        return p;
    };
    int*      deg      = (int*)     alloc((size_t)NN * 4);
    float*    dis      = (float*)   alloc((size_t)NN * 4);
    int*      rowstart = (int*)     alloc((size_t)NN * 4);
    int*      cur      = (int*)     alloc((size_t)NN * 4);
    int*      bpart    = (int*)     alloc((size_t)512 * 4);
    int*      scols    = (int*)     alloc((size_t)NE * 4);
    ushort_t* tPN      = (ushort_t*)alloc((size_t)NN * 128 * 2);   // layer-1 fp16 table, 25.6 MB
    ushort_t* tPN2     = (ushort_t*)alloc((size_t)NN * 128 * 2);   // layer-2 fp16 table, 25.6 MB
    float*    part     = (float*)   alloc((size_t)SUMW * D * 4);   // 256 KB
    uint4*    wfrag    = (uint4*)   alloc((size_t)2 * 1024 * 16);  // W1|W2 bf16 hi/lo frags, 32 KB
    // ~60 MB total

    hipMemsetAsync(deg, 0, (size_t)NN * 4, stream);

    // preprocessing: direct CSR build (hist -> 3-step scan -> scatter)
    hist_k<<<NEB + 1, 256, 0, stream>>>(erows, deg, NE, W1, W2, wfrag);
    scan1_k<<<NSB, SB, 0, stream>>>(deg, bpart);
    scan2_k<<<1, 512, 0, stream>>>(bpart);
    scan3_k<<<NSB, SB, 0, stream>>>(deg, bpart, rowstart, cur, dis);
    scatter_k<<<NEB, 256, 0, stream>>>(erows, ecols, cur, scols, NE);

    // layer 1 GEMM: tPN[c] = [dis[c]*(x[c]@W1) | dis[c]*(x[perm[c]]@W1)]
    gemm1_k<<<(NN / 16 + 3) / 4, 256, 0, stream>>>(x, wfrag, tPN, perm, dis, NN);

    // fused layer-1 aggregate (+b1,PReLU) + layer-2 GEMM -> scaled fp16 table
    agg_gemm_k<<<NN / 16, 256, 0, stream>>>(tPN, tPN2, dis, rowstart, deg, scols,
                                            b1, prelu_a, wfrag + 1024);

    // final aggregate (+b2) -> outputs
    agg_dual_k<<<(NN + 3) / 4, 256, 0, stream>>>(tPN2, outP, outN, dis, rowstart, deg,
                                                 scols, b2, NN);

    // summary = sigmoid(mean(positive, axis=0))
    summary_partial_k<<<256, 256, 0, stream>>>(outP, part, NN);
    summary_final_k<<<1, 256, 0, stream>>>(part, outS, NN);
}

// Round 8
// 323.074 us; speedup vs baseline: 1.2872x; 1.2872x over previous
//
#include <hip/hip_runtime.h>
#include <hip/hip_fp16.h>
#include <math.h>

namespace {

constexpr int NN = 100000;   // nodes
constexpr int NE = 1000000;  // edges
constexpr int D  = 64;       // feature dim

constexpr int RPB_LOG = 8;                        // rows per bucket = 256
constexpr int RPB = 1 << RPB_LOG;
constexpr int NBUK = (NN + RPB - 1) >> RPB_LOG;   // 391 buckets
constexpr int CAP = 4096;                         // bucket capacity (mean 2558, +30 sigma)
constexpr int TILE = 2048;                        // edges per bin tile
constexpr int NTILES = (NE + TILE - 1) / TILE;    // 489
constexpr int SUMW = 1024;                        // summary partial waves

using ushort_t = unsigned short;
typedef __attribute__((ext_vector_type(8))) short short8;  // 8 bf16 (4 VGPRs)
typedef __attribute__((ext_vector_type(4))) float f32x4;   // MFMA 16x16 accumulator

union FragU { uint4 v; short8 s; };

// split two fp32 into packed bf16 hi parts and packed bf16 lo (residual) parts.
__device__ inline void split2(float f0, float f1, unsigned int& hi, unsigned int& lo) {
    unsigned int u0 = __float_as_uint(f0);
    unsigned int u1 = __float_as_uint(f1);
    hi = (u0 >> 16) | (u1 & 0xffff0000u);
    float l0 = f0 - __uint_as_float(u0 & 0xffff0000u);
    float l1 = f1 - __uint_as_float(u1 & 0xffff0000u);
    lo = (__float_as_uint(l0) >> 16) | (__float_as_uint(l1) & 0xffff0000u);
}

__device__ inline unsigned int packh(float a, float b) {   // 2x fp16 (RNE) packed
    union { __half2 h; unsigned int u; } cv;
    cv.h = __float22half2_rn(make_float2(a, b));
    return cv.u;
}

__device__ inline float2 h2f(unsigned int v) {
    union { unsigned int u; __half2 h; } cv;
    cv.u = v;
    return __half22float2(cv.h);
}

// Fused Phase A + weight-fragment precompute.
// Blocks [0, NTILES): bin edges into 391 fixed-capacity row-range buckets
// using LDS-local atomics + one global atomic per (block,bucket).
//   Payload packed: (r & 255) << 17 | c   (c < 2^17)
// Block NTILES: build MFMA A-operand fragments for W1|W2 (bf16 hi/lo),
//   layout per matrix: [ftile(4)][ktile(2)][hi/lo(2)][lane(64)] x 16B;
//   lane l holds A[m][k], m = ft*16 + (l&15), k = kt*32 + (l>>4)*8 + j.
// NOTE (R7 lesson): edge-scale DEVICE atomics / random 4B stores cost ~70us
// per pass on MI355X (cross-XCD coherence + 16x RFO amplification). Keep
// binning LDS-local with bucket-chunked payload writes.
__global__ void binw_k(const int* __restrict__ rows, const int* __restrict__ cols,
                       int* __restrict__ bcount, unsigned int* __restrict__ binned, int e,
                       const float* __restrict__ W1, const float* __restrict__ W2,
                       uint4* __restrict__ fb) {
    __shared__ int hist[NBUK];
    __shared__ int gbase[NBUK];
    __shared__ int lofs[NBUK];
    if (blockIdx.x == NTILES) {
        int lane = threadIdx.x;
        if (lane < 64) {
            for (int w = 0; w < 2; ++w) {
                const float* W = (w != 0) ? W2 : W1;
                uint4* out = fb + w * 1024;
                for (int ft = 0; ft < 4; ++ft) {
                    for (int kt = 0; kt < 2; ++kt) {
                        int m  = ft * 16 + (lane & 15);
                        int k0 = kt * 32 + (lane >> 4) * 8;
                        unsigned int hi0, lo0, hi1, lo1, hi2, lo2, hi3, lo3;
                        split2(W[(k0 + 0) * 64 + m], W[(k0 + 1) * 64 + m], hi0, lo0);
                        split2(W[(k0 + 2) * 64 + m], W[(k0 + 3) * 64 + m], hi1, lo1);
                        split2(W[(k0 + 4) * 64 + m], W[(k0 + 5) * 64 + m], hi2, lo2);
                        split2(W[(k0 + 6) * 64 + m], W[(k0 + 7) * 64 + m], hi3, lo3);
                        out[((ft * 2 + kt) * 2 + 0) * 64 + lane] = make_uint4(hi0, hi1, hi2, hi3);
                        out[((ft * 2 + kt) * 2 + 1) * 64 + lane] = make_uint4(lo0, lo1, lo2, lo3);
                    }
                }
            }
        }
        return;
    }
    int base = blockIdx.x * TILE;
    for (int i = threadIdx.x; i < NBUK; i += blockDim.x) {
        hist[i] = 0;
        lofs[i] = 0;
    }
    __syncthreads();
    int r[8];
    int c[8];
    int bk[8];
#pragma unroll
    for (int j = 0; j < 8; ++j) {
        int i = base + j * 256 + threadIdx.x;
        if (i < e) {
            r[j] = rows[i];
            c[j] = cols[i];
            bk[j] = r[j] >> RPB_LOG;
            atomicAdd(&hist[bk[j]], 1);
        } else {
            bk[j] = -1;
        }
    }
    __syncthreads();
    for (int b = threadIdx.x; b < NBUK; b += blockDim.x) {
        int h = hist[b];
        gbase[b] = h ? atomicAdd(&bcount[b], h) : 0;
    }
    __syncthreads();
#pragma unroll
    for (int j = 0; j < 8; ++j) {
        if (bk[j] >= 0) {
            int l = gbase[bk[j]] + atomicAdd(&lofs[bk[j]], 1);
            if (l < CAP) {
                unsigned int v = ((unsigned int)(r[j] & (RPB - 1)) << 17) | (unsigned int)c[j];
                binned[(size_t)bk[j] * CAP + l] = v;
            }
        }
    }
}

// Phase B: per-bucket counting sort + per-row deg/rowstart/dis production.
// Bucket base (exclusive scan of bcount over buckets < b) computed in-block.
__global__ void bucket_sort_k(const unsigned int* __restrict__ binned,
                              const int* __restrict__ bcount,
                              int* __restrict__ scols, int* __restrict__ rowstart,
                              int* __restrict__ deg, float* __restrict__ dis) {
    __shared__ int lcur[RPB];
    __shared__ int srs[RPB];
    __shared__ int wsum[8];
    __shared__ int redpart[8];
    __shared__ int sbase;
    int b = blockIdx.x;
    int row0 = b << RPB_LOG;
    int nrows = min(RPB, NN - row0);
    int cnt = bcount[b];
    const unsigned int* src = binned + (size_t)b * CAP;
    int tid = threadIdx.x;
    int lane = tid & 63;
    int wid = tid >> 6;

    // in-block exclusive bucket base: sum of bcount[i] for i < b
    int bv = (tid < NBUK && tid < b) ? bcount[tid] : 0;
    int bs = bv;
#pragma unroll
    for (int off = 1; off < 64; off <<= 1) {
        bs += __shfl_xor(bs, off, 64);
    }
    if (lane == 0) redpart[wid] = bs;
    __syncthreads();
    if (tid == 0) {
        int t = 0;
        for (int w = 0; w < 8; ++w) t += redpart[w];
        sbase = t;
    }
    if (tid < RPB) {
        lcur[tid] = 0;
    }
    __syncthreads();
    int bb = sbase;

    for (int i = tid; i < cnt; i += blockDim.x) {
        atomicAdd(&lcur[src[i] >> 17], 1);
    }
    __syncthreads();
    int d = (tid < nrows) ? lcur[tid] : 0;
    int inc = d;
#pragma unroll
    for (int off = 1; off < 64; off <<= 1) {
        int t = __shfl_up(inc, off);
        if (lane >= off) inc += t;
    }
    if (lane == 63) wsum[wid] = inc;
    __syncthreads();
    int wpre = 0;
    for (int w = 0; w < wid; ++w) wpre += wsum[w];
    int gstart = bb + wpre + inc - d;   // global exclusive prefix
    if (tid < nrows) {
        rowstart[row0 + tid] = gstart;
        deg[row0 + tid] = d;
        dis[row0 + tid] = rsqrtf((float)(d + 1));  // +1 self-loop
    }
    __syncthreads();
    if (tid < RPB) {
        srs[tid] = gstart;
        lcur[tid] = 0;
    }
    __syncthreads();
    for (int i = tid; i < cnt; i += blockDim.x) {
        unsigned int v = src[i];
        int rl = (int)(v >> 17);
        int pos = srs[rl] + atomicAdd(&lcur[rl], 1);
        scols[pos] = (int)(v & 0x1FFFFu);
    }
}

// Layer-1 MFMA GEMM: per output row c computes BOTH products
//   P[c] = dis[c]*(x[c]@W1),  N[c] = dis[c]*(x[perm[c]]@W1)
// via mfma_f32_16x16x32_bf16 with bf16 hi/lo split (~fp32 accuracy).
// One wave per 16-row tile; dense 256B interleaved-row writes (no scatter).
__global__ void gemm1_k(const float* __restrict__ in, const uint4* __restrict__ wf,
                        ushort_t* __restrict__ tPN, const int* __restrict__ perm,
                        const float* __restrict__ dis, int n) {
    int lane  = threadIdx.x & 63;
    int wtile = (int)((blockIdx.x * blockDim.x + threadIdx.x) >> 6);
    if (wtile * 16 >= n) return;
    int node = wtile * 16 + (lane & 15);
    int kg   = lane >> 4;  // 0..3

    FragU whi[4][2];
    FragU wlo[4][2];
#pragma unroll
    for (int ft = 0; ft < 4; ++ft) {
#pragma unroll
        for (int kt = 0; kt < 2; ++kt) {
            whi[ft][kt].v = wf[((ft * 2 + kt) * 2 + 0) * 64 + lane];
            wlo[ft][kt].v = wf[((ft * 2 + kt) * 2 + 1) * 64 + lane];
        }
    }

    const float4* xr = (const float4*)in;
    size_t rbase = (size_t)node * 16 + (size_t)(kg * 2);
    int pnode = perm[node];
    size_t pbase = (size_t)pnode * 16 + (size_t)(kg * 2);
    f32x4 accP[4];
    f32x4 accN[4];
#pragma unroll
    for (int ft = 0; ft < 4; ++ft) {
        accP[ft] = f32x4{0.f, 0.f, 0.f, 0.f};
        accN[ft] = f32x4{0.f, 0.f, 0.f, 0.f};
    }
#pragma unroll
    for (int kt = 0; kt < 2; ++kt) {
        float4 a0 = xr[rbase + kt * 8];
        float4 a1 = xr[rbase + kt * 8 + 1];
        float4 g0 = xr[pbase + kt * 8];
        float4 g1 = xr[pbase + kt * 8 + 1];
        unsigned int h0, l0, h1, l1, h2, l2, h3, l3;
        split2(a0.x, a0.y, h0, l0);
        split2(a0.z, a0.w, h1, l1);
        split2(a1.x, a1.y, h2, l2);
        split2(a1.z, a1.w, h3, l3);
        FragU xhiP, xloP;
        xhiP.v = make_uint4(h0, h1, h2, h3);
        xloP.v = make_uint4(l0, l1, l2, l3);
        split2(g0.x, g0.y, h0, l0);
        split2(g0.z, g0.w, h1, l1);
        split2(g1.x, g1.y, h2, l2);
        split2(g1.z, g1.w, h3, l3);
        FragU xhiN, xloN;
        xhiN.v = make_uint4(h0, h1, h2, h3);
        xloN.v = make_uint4(l0, l1, l2, l3);
#pragma unroll
        for (int ft = 0; ft < 4; ++ft) {
            accP[ft] = __builtin_amdgcn_mfma_f32_16x16x32_bf16(whi[ft][kt].s, xhiP.s, accP[ft], 0, 0, 0);
            accP[ft] = __builtin_amdgcn_mfma_f32_16x16x32_bf16(whi[ft][kt].s, xloP.s, accP[ft], 0, 0, 0);
            accP[ft] = __builtin_amdgcn_mfma_f32_16x16x32_bf16(wlo[ft][kt].s, xhiP.s, accP[ft], 0, 0, 0);
            accN[ft] = __builtin_amdgcn_mfma_f32_16x16x32_bf16(whi[ft][kt].s, xhiN.s, accN[ft], 0, 0, 0);
            accN[ft] = __builtin_amdgcn_mfma_f32_16x16x32_bf16(whi[ft][kt].s, xloN.s, accN[ft], 0, 0, 0);
            accN[ft] = __builtin_amdgcn_mfma_f32_16x16x32_bf16(wlo[ft][kt].s, xhiN.s, accN[ft], 0, 0, 0);
        }
    }
    int fo = kg * 4;
    float s = dis[node];
    ushort_t* p = tPN + (size_t)node * 128;
#pragma unroll
    for (int ft = 0; ft < 4; ++ft) {
        uint2 up = make_uint2(packh(s * accP[ft][0], s * accP[ft][1]),
                              packh(s * accP[ft][2], s * accP[ft][3]));
        *(uint2*)(p + ft * 16 + fo) = up;
        uint2 un = make_uint2(packh(s * accN[ft][0], s * accN[ft][1]),
                              packh(s * accN[ft][2], s * accN[ft][3]));
        *(uint2*)(p + 64 + ft * 16 + fo) = un;
    }
}

// FUSED layer-1 aggregate + layer-2 GEMM. One block (4 waves) owns 16 rows.
// Phase 1 (gather, R2-proven structure): each wave aggregates 4 rows
// sequentially; lanes 0-31 = P half, 32-63 = N half, 2 feats/lane/4B-load;
// scols reads wave-uniform (scalar). H row (post bias+PReLU) parked in LDS
// [half][16][68] fp32. Phase 2 (MFMA): waves 0,1 -> P, waves 2,3 -> N;
// 2 ftiles/wave; same split2 hi/lo math as gemm1; epilogue scales by
// dis[row], writes fp16 table tOut (dense 8B stores).
__global__ void agg_gemm_k(const ushort_t* __restrict__ tIn, ushort_t* __restrict__ tOut,
                           const float* __restrict__ dis,
                           const int* __restrict__ rowstart, const int* __restrict__ deg,
                           const int* __restrict__ scols,
                           const float* __restrict__ bias, const float* __restrict__ prelu_a,
                           const uint4* __restrict__ wf) {
    __shared__ float Hs[2][16][68];
    int tid = threadIdx.x;
    int lane = tid & 63;
    int wv = tid >> 6;                 // 0..3
    int row0 = blockIdx.x * 16;
    int hl = lane & 31;
    int half = lane >> 5;
    size_t lofs = (size_t)(half * 64 + hl * 2);
    float aPr = *prelu_a;

    for (int rr = 0; rr < 4; ++rr) {
        int r = row0 + wv * 4 + rr;
        int rs   = __builtin_amdgcn_readfirstlane(r);
        int base = __builtin_amdgcn_readfirstlane(rowstart[rs]);
        int dg   = __builtin_amdgcn_readfirstlane(deg[rs]);
        float dr = dis[rs];
        unsigned int sv = *(const unsigned int*)(tIn + (size_t)rs * 128 + lofs);
        float2 fs = h2f(sv);
        float a0 = fs.x;
        float a1 = fs.y;     // self-loop term
        int j = 0;
        for (; j + 4 <= dg; j += 4) {
            int c0 = scols[base + j];
            int c1 = scols[base + j + 1];
            int c2 = scols[base + j + 2];
            int c3 = scols[base + j + 3];
            unsigned int v0 = *(const unsigned int*)(tIn + (size_t)c0 * 128 + lofs);
            unsigned int v1 = *(const unsigned int*)(tIn + (size_t)c1 * 128 + lofs);
            unsigned int v2 = *(const unsigned int*)(tIn + (size_t)c2 * 128 + lofs);
            unsigned int v3 = *(const unsigned int*)(tIn + (size_t)c3 * 128 + lofs);
            float2 f0 = h2f(v0);
            float2 f1 = h2f(v1);
            float2 f2 = h2f(v2);
            float2 f3 = h2f(v3);
            a0 += f0.x + f1.x + f2.x + f3.x;
            a1 += f0.y + f1.y + f2.y + f3.y;
        }
        for (; j < dg; ++j) {
            int c = scols[base + j];
            unsigned int v = *(const unsigned int*)(tIn + (size_t)c * 128 + lofs);
            float2 f = h2f(v);
            a0 += f.x;
            a1 += f.y;
        }
        float2 bv = *(const float2*)(bias + 2 * hl);
        float v0 = fmaf(dr, a0, bv.x);
        float v1 = fmaf(dr, a1, bv.y);
        v0 = v0 >= 0.f ? v0 : aPr * v0;
        v1 = v1 >= 0.f ? v1 : aPr * v1;
        int rl = wv * 4 + rr;
        Hs[half][rl][2 * hl]     = v0;
        Hs[half][rl][2 * hl + 1] = v1;
    }
    __syncthreads();

    // layer-2: out[row] = dis[row] * (H[row] @ W2), per half
    int kg = lane >> 4;
    int nd = lane & 15;
    int hsel = wv >> 1;                // waves 0,1 -> P; 2,3 -> N
    int ftb = (wv & 1) * 2;            // ftiles {0,1} or {2,3}
    FragU whi[2][2];
    FragU wlo[2][2];
#pragma unroll
    for (int f2 = 0; f2 < 2; ++f2) {
#pragma unroll
        for (int kt = 0; kt < 2; ++kt) {
            whi[f2][kt].v = wf[(((ftb + f2) * 2 + kt) * 2 + 0) * 64 + lane];
            wlo[f2][kt].v = wf[(((ftb + f2) * 2 + kt) * 2 + 1) * 64 + lane];
        }
    }
    f32x4 acc[2];
    acc[0] = f32x4{0.f, 0.f, 0.f, 0.f};
    acc[1] = f32x4{0.f, 0.f, 0.f, 0.f};
#pragma unroll
    for (int kt = 0; kt < 2; ++kt) {
        float4 a0 = *(const float4*)&Hs[hsel][nd][kt * 32 + kg * 8];
        float4 a1 = *(const float4*)&Hs[hsel][nd][kt * 32 + kg * 8 + 4];
        unsigned int h0, l0, h1, l1, h2, l2, h3, l3;
        split2(a0.x, a0.y, h0, l0);
        split2(a0.z, a0.w, h1, l1);
        split2(a1.x, a1.y, h2, l2);
        split2(a1.z, a1.w, h3, l3);
        FragU xhi, xlo;
        xhi.v = make_uint4(h0, h1, h2, h3);
        xlo.v = make_uint4(l0, l1, l2, l3);
#pragma unroll
        for (int f2 = 0; f2 < 2; ++f2) {
            acc[f2] = __builtin_amdgcn_mfma_f32_16x16x32_bf16(whi[f2][kt].s, xhi.s, acc[f2], 0, 0, 0);
            acc[f2] = __builtin_amdgcn_mfma_f32_16x16x32_bf16(whi[f2][kt].s, xlo.s, acc[f2], 0, 0, 0);
            acc[f2] = __builtin_amdgcn_mfma_f32_16x16x32_bf16(wlo[f2][kt].s, xhi.s, acc[f2], 0, 0, 0);
        }
    }
    float s = dis[row0 + nd];
    ushort_t* p = tOut + (size_t)(row0 + nd) * 128 + hsel * 64;
    int fo = kg * 4;
#pragma unroll
    for (int f2 = 0; f2 < 2; ++f2) {
        uint2 u = make_uint2(packh(s * acc[f2][0], s * acc[f2][1]),
                             packh(s * acc[f2][2], s * acc[f2][3]));
        *(uint2*)(p + (ftb + f2) * 16 + fo) = u;
    }
}

// Dual gather-aggregate over the interleaved fp16 table (final layer).
// One wave per row; lanes 0-31 = P half, 32-63 = N half; 2 feats/lane.
// outX[r] = dis[r]*(sum_j tX[c_j] + tX[r]) + b
__global__ void agg_dual_k(const ushort_t* __restrict__ tPN,
                           float* __restrict__ dstP, float* __restrict__ dstN,
                           const float* __restrict__ dis,
                           const int* __restrict__ rowstart, const int* __restrict__ deg,
                           const int* __restrict__ scols,
                           const float* __restrict__ bias, int n) {
    int lane = threadIdx.x & 63;
    int hl = lane & 31;
    int half = lane >> 5;
    int r = blockIdx.x * (blockDim.x >> 6) + (threadIdx.x >> 6);
    if (r >= n) return;
    int rs   = __builtin_amdgcn_readfirstlane(r);
    int base = __builtin_amdgcn_readfirstlane(rowstart[rs]);
    int dg   = __builtin_amdgcn_readfirstlane(deg[rs]);
    float dr = dis[rs];
    size_t lofs = (size_t)(half * 64 + hl * 2);
    unsigned int sv = *(const unsigned int*)(tPN + (size_t)rs * 128 + lofs);
    float2 fs = h2f(sv);
    float a0 = fs.x;
    float a1 = fs.y;     // self-loop term
    int j = 0;
    for (; j + 4 <= dg; j += 4) {
        int c0 = scols[base + j];
        int c1 = scols[base + j + 1];
        int c2 = scols[base + j + 2];
        int c3 = scols[base + j + 3];
        unsigned int v0 = *(const unsigned int*)(tPN + (size_t)c0 * 128 + lofs);
        unsigned int v1 = *(const unsigned int*)(tPN + (size_t)c1 * 128 + lofs);
        unsigned int v2 = *(const unsigned int*)(tPN + (size_t)c2 * 128 + lofs);
        unsigned int v3 = *(const unsigned int*)(tPN + (size_t)c3 * 128 + lofs);
        float2 f0 = h2f(v0);
        float2 f1 = h2f(v1);
        float2 f2 = h2f(v2);
        float2 f3 = h2f(v3);
        a0 += f0.x + f1.x + f2.x + f3.x;
        a1 += f0.y + f1.y + f2.y + f3.y;
    }
    for (; j < dg; ++j) {
        int c = scols[base + j];
        unsigned int v = *(const unsigned int*)(tPN + (size_t)c * 128 + lofs);
        float2 f = h2f(v);
        a0 += f.x;
        a1 += f.y;
    }
    float2 bv = *(const float2*)(bias + 2 * hl);
    float v0 = fmaf(dr, a0, bv.x);
    float v1 = fmaf(dr, a1, bv.y);
    float* dst = half ? dstN : dstP;
    *(float2*)(dst + (size_t)rs * D + 2 * hl) = float2{v0, v1};
}

// atomic-free summary: per-wave partial sums into part[wave][64]
__global__ void summary_partial_k(const float* __restrict__ pos, float* __restrict__ part, int n) {
    int lane = threadIdx.x & 63;
    int wave = (blockIdx.x * blockDim.x + threadIdx.x) >> 6;
    int nw = (gridDim.x * blockDim.x) >> 6;
    float s = 0.f;
    for (int r = wave; r < n; r += nw) {
        s += pos[(size_t)r * D + lane];
    }
    part[(size_t)wave * D + lane] = s;
}

// 256 threads: 4-way split over the SUMW partials + LDS reduce (R5's 1-wave
// serial 256KB read was ~15-25us)
__global__ void summary_final_k(const float* __restrict__ part, float* __restrict__ out, int n) {
    __shared__ float red[4][64];
    int f = threadIdx.x & 63;
    int g = threadIdx.x >> 6;
    float s = 0.f;
    for (int w = g; w < SUMW; w += 4) {
        s += part[(size_t)w * D + f];
    }
    red[g][f] = s;
    __syncthreads();
    if (threadIdx.x < 64) {
        float m = (red[0][f] + red[1][f] + red[2][f] + red[3][f]) / (float)n;
        out[f] = 1.f / (1.f + expf(-m));
    }
}

} // namespace

extern "C" void kernel_launch(void* const* d_in, const int* in_sizes, int n_in,
                              void* d_out, int out_size, void* d_ws, size_t ws_size,
                              hipStream_t stream) {
    (void)in_sizes; (void)n_in; (void)out_size; (void)ws_size;
    const float* x       = (const float*)d_in[0];
    const int*   ei      = (const int*)  d_in[1];
    const int*   perm    = (const int*)  d_in[2];
    const float* W1      = (const float*)d_in[3];
    const float* b1      = (const float*)d_in[4];
    const float* prelu_a = (const float*)d_in[5];
    const float* W2      = (const float*)d_in[6];
    const float* b2      = (const float*)d_in[7];

    float* outP = (float*)d_out;
    float* outN = outP + (size_t)NN * D;
    float* outS = outN + (size_t)NN * D;

    const int* erows = ei;
    const int* ecols = ei + NE;

    char* ws = (char*)d_ws;
    size_t off = 0;
    auto alloc = [&](size_t bytes) {
        void* p = ws + off;
        off = (off + bytes + 255) & ~(size_t)255;
        return p;
    };
    int*      deg      = (int*)     alloc((size_t)NN * 4);
    float*    dis      = (float*)   alloc((size_t)NN * 4);
    int*      rowstart = (int*)     alloc((size_t)NN * 4);
    int*      bcount   = (int*)     alloc((size_t)NBUK * 4);
    unsigned int* binned = (unsigned int*)alloc((size_t)NBUK * CAP * 4);  // 6.4 MB
    int*      scols    = (int*)     alloc((size_t)NE * 4);
    ushort_t* tPN      = (ushort_t*)alloc((size_t)NN * 128 * 2);   // layer-1 fp16 table, 25.6 MB
    ushort_t* tPN2     = (ushort_t*)alloc((size_t)NN * 128 * 2);   // layer-2 fp16 table, 25.6 MB
    float*    part     = (float*)   alloc((size_t)SUMW * D * 4);   // 256 KB
    uint4*    wfrag    = (uint4*)   alloc((size_t)2 * 1024 * 16);  // W1|W2 bf16 hi/lo frags, 32 KB
    // ~65 MB total

    hipMemsetAsync(bcount, 0, (size_t)NBUK * 4, stream);

    // preprocessing: fused bin+wfrag -> per-bucket sort (scan in-block)
    binw_k<<<NTILES + 1, 256, 0, stream>>>(erows, ecols, bcount, binned, NE, W1, W2, wfrag);
    bucket_sort_k<<<NBUK, 512, 0, stream>>>(binned, bcount, scols, rowstart, deg, dis);

    // layer 1 GEMM: tPN[c] = [dis[c]*(x[c]@W1) | dis[c]*(x[perm[c]]@W1)]
    gemm1_k<<<(NN / 16 + 3) / 4, 256, 0, stream>>>(x, wfrag, tPN, perm, dis, NN);

    // fused layer-1 aggregate (+b1,PReLU) + layer-2 GEMM -> scaled fp16 table
    agg_gemm_k<<<NN / 16, 256, 0, stream>>>(tPN, tPN2, dis, rowstart, deg, scols,
                                            b1, prelu_a, wfrag + 1024);

    // final aggregate (+b2) -> outputs
    agg_dual_k<<<(NN + 3) / 4, 256, 0, stream>>>(tPN2, outP, outN, dis, rowstart, deg,
                                                 scols, b2, NN);

    // summary = sigmoid(mean(positive, axis=0))
    summary_partial_k<<<256, 256, 0, stream>>>(outP, part, NN);
    summary_final_k<<<1, 256, 0, stream>>>(part, outS, NN);
}

// Round 9
// 291.068 us; speedup vs baseline: 1.4287x; 1.1100x over previous
//
#include <hip/hip_runtime.h>
#include <hip/hip_fp16.h>
#include <math.h>

namespace {

constexpr int NN = 100000;   // nodes
constexpr int NE = 1000000;  // edges
constexpr int D  = 64;       // feature dim

constexpr int RPB_LOG = 8;                        // rows per bucket = 256
constexpr int RPB = 1 << RPB_LOG;
constexpr int NBUK = (NN + RPB - 1) >> RPB_LOG;   // 391 buckets
constexpr int CAP = 4096;                         // bucket capacity (mean 2558, +30 sigma)
constexpr int TILE = 2048;                        // edges per bin tile
constexpr int NTILES = (NE + TILE - 1) / TILE;    // 489

using ushort_t = unsigned short;
typedef __attribute__((ext_vector_type(8))) short short8;  // 8 bf16 (4 VGPRs)
typedef __attribute__((ext_vector_type(4))) float f32x4;   // MFMA 16x16 accumulator

union FragU { uint4 v; short8 s; };

// split two fp32 into packed bf16 hi parts and packed bf16 lo (residual) parts.
__device__ inline void split2(float f0, float f1, unsigned int& hi, unsigned int& lo) {
    unsigned int u0 = __float_as_uint(f0);
    unsigned int u1 = __float_as_uint(f1);
    hi = (u0 >> 16) | (u1 & 0xffff0000u);
    float l0 = f0 - __uint_as_float(u0 & 0xffff0000u);
    float l1 = f1 - __uint_as_float(u1 & 0xffff0000u);
    lo = (__float_as_uint(l0) >> 16) | (__float_as_uint(l1) & 0xffff0000u);
}

__device__ inline unsigned int packh(float a, float b) {   // 2x fp16 (RNE) packed
    union { __half2 h; unsigned int u; } cv;
    cv.h = __float22half2_rn(make_float2(a, b));
    return cv.u;
}

__device__ inline float2 h2f(unsigned int v) {
    union { unsigned int u; __half2 h; } cv;
    cv.u = v;
    return __half22float2(cv.h);
}

// Fused Phase A + weight-fragment precompute.
// Blocks [0, NTILES): bin edges into 391 fixed-capacity row-range buckets
// using LDS-local atomics + one global atomic per (block,bucket).
//   Payload packed: (r & 255) << 17 | c   (c < 2^17)
// Block NTILES: build MFMA A-operand fragments for W1|W2 (bf16 hi/lo),
//   layout per matrix: [ftile(4)][ktile(2)][hi/lo(2)][lane(64)] x 16B;
//   lane l holds A[m][k], m = ft*16 + (l&15), k = kt*32 + (l>>4)*8 + j.
// NOTE (R7 lesson): edge-scale DEVICE atomics / random 4B stores cost ~70us
// per pass on MI355X (cross-XCD coherence + 16x RFO amplification). Keep
// binning LDS-local with bucket-chunked payload writes.
__global__ void binw_k(const int* __restrict__ rows, const int* __restrict__ cols,
                       int* __restrict__ bcount, unsigned int* __restrict__ binned, int e,
                       const float* __restrict__ W1, const float* __restrict__ W2,
                       uint4* __restrict__ fb) {
    __shared__ int hist[NBUK];
    __shared__ int gbase[NBUK];
    __shared__ int lofs[NBUK];
    if (blockIdx.x == NTILES) {
        int lane = threadIdx.x;
        if (lane < 64) {
            for (int w = 0; w < 2; ++w) {
                const float* W = (w != 0) ? W2 : W1;
                uint4* out = fb + w * 1024;
                for (int ft = 0; ft < 4; ++ft) {
                    for (int kt = 0; kt < 2; ++kt) {
                        int m  = ft * 16 + (lane & 15);
                        int k0 = kt * 32 + (lane >> 4) * 8;
                        unsigned int hi0, lo0, hi1, lo1, hi2, lo2, hi3, lo3;
                        split2(W[(k0 + 0) * 64 + m], W[(k0 + 1) * 64 + m], hi0, lo0);
                        split2(W[(k0 + 2) * 64 + m], W[(k0 + 3) * 64 + m], hi1, lo1);
                        split2(W[(k0 + 4) * 64 + m], W[(k0 + 5) * 64 + m], hi2, lo2);
                        split2(W[(k0 + 6) * 64 + m], W[(k0 + 7) * 64 + m], hi3, lo3);
                        out[((ft * 2 + kt) * 2 + 0) * 64 + lane] = make_uint4(hi0, hi1, hi2, hi3);
                        out[((ft * 2 + kt) * 2 + 1) * 64 + lane] = make_uint4(lo0, lo1, lo2, lo3);
                    }
                }
            }
        }
        return;
    }
    int base = blockIdx.x * TILE;
    for (int i = threadIdx.x; i < NBUK; i += blockDim.x) {
        hist[i] = 0;
        lofs[i] = 0;
    }
    __syncthreads();
    int r[8];
    int c[8];
    int bk[8];
#pragma unroll
    for (int j = 0; j < 8; ++j) {
        int i = base + j * 256 + threadIdx.x;
        if (i < e) {
            r[j] = rows[i];
            c[j] = cols[i];
            bk[j] = r[j] >> RPB_LOG;
            atomicAdd(&hist[bk[j]], 1);
        } else {
            bk[j] = -1;
        }
    }
    __syncthreads();
    for (int b = threadIdx.x; b < NBUK; b += blockDim.x) {
        int h = hist[b];
        gbase[b] = h ? atomicAdd(&bcount[b], h) : 0;
    }
    __syncthreads();
#pragma unroll
    for (int j = 0; j < 8; ++j) {
        if (bk[j] >= 0) {
            int l = gbase[bk[j]] + atomicAdd(&lofs[bk[j]], 1);
            if (l < CAP) {
                unsigned int v = ((unsigned int)(r[j] & (RPB - 1)) << 17) | (unsigned int)c[j];
                binned[(size_t)bk[j] * CAP + l] = v;
            }
        }
    }
}

// Phase B: per-bucket counting sort + per-row deg/rowstart/dis production.
// Bucket base (exclusive scan of bcount over buckets < b) computed in-block.
__global__ void bucket_sort_k(const unsigned int* __restrict__ binned,
                              const int* __restrict__ bcount,
                              int* __restrict__ scols, int* __restrict__ rowstart,
                              int* __restrict__ deg, float* __restrict__ dis) {
    __shared__ int lcur[RPB];
    __shared__ int srs[RPB];
    __shared__ int wsum[8];
    __shared__ int redpart[8];
    __shared__ int sbase;
    int b = blockIdx.x;
    int row0 = b << RPB_LOG;
    int nrows = min(RPB, NN - row0);
    int cnt = bcount[b];
    const unsigned int* src = binned + (size_t)b * CAP;
    int tid = threadIdx.x;
    int lane = tid & 63;
    int wid = tid >> 6;

    // in-block exclusive bucket base: sum of bcount[i] for i < b
    int bv = (tid < NBUK && tid < b) ? bcount[tid] : 0;
    int bs = bv;
#pragma unroll
    for (int off = 1; off < 64; off <<= 1) {
        bs += __shfl_xor(bs, off, 64);
    }
    if (lane == 0) redpart[wid] = bs;
    __syncthreads();
    if (tid == 0) {
        int t = 0;
        for (int w = 0; w < 8; ++w) t += redpart[w];
        sbase = t;
    }
    if (tid < RPB) {
        lcur[tid] = 0;
    }
    __syncthreads();
    int bb = sbase;

    for (int i = tid; i < cnt; i += blockDim.x) {
        atomicAdd(&lcur[src[i] >> 17], 1);
    }
    __syncthreads();
    int d = (tid < nrows) ? lcur[tid] : 0;
    int inc = d;
#pragma unroll
    for (int off = 1; off < 64; off <<= 1) {
        int t = __shfl_up(inc, off);
        if (lane >= off) inc += t;
    }
    if (lane == 63) wsum[wid] = inc;
    __syncthreads();
    int wpre = 0;
    for (int w = 0; w < wid; ++w) wpre += wsum[w];
    int gstart = bb + wpre + inc - d;   // global exclusive prefix
    if (tid < nrows) {
        rowstart[row0 + tid] = gstart;
        deg[row0 + tid] = d;
        dis[row0 + tid] = rsqrtf((float)(d + 1));  // +1 self-loop
    }
    __syncthreads();
    if (tid < RPB) {
        srs[tid] = gstart;
        lcur[tid] = 0;
    }
    __syncthreads();
    for (int i = tid; i < cnt; i += blockDim.x) {
        unsigned int v = src[i];
        int rl = (int)(v >> 17);
        int pos = srs[rl] + atomicAdd(&lcur[rl], 1);
        scols[pos] = (int)(v & 0x1FFFFu);
    }
}

// Layer-1 MFMA GEMM: per output row c computes BOTH products
//   P[c] = dis[c]*(x[c]@W1),  N[c] = dis[c]*(x[perm[c]]@W1)
// via mfma_f32_16x16x32_bf16 with bf16 hi/lo split (~fp32 accuracy).
// One wave per 16-row tile; dense 256B interleaved-row writes (no scatter).
__global__ void gemm1_k(const float* __restrict__ in, const uint4* __restrict__ wf,
                        ushort_t* __restrict__ tPN, const int* __restrict__ perm,
                        const float* __restrict__ dis, int n) {
    int lane  = threadIdx.x & 63;
    int wtile = (int)((blockIdx.x * blockDim.x + threadIdx.x) >> 6);
    if (wtile * 16 >= n) return;
    int node = wtile * 16 + (lane & 15);
    int kg   = lane >> 4;  // 0..3

    FragU whi[4][2];
    FragU wlo[4][2];
#pragma unroll
    for (int ft = 0; ft < 4; ++ft) {
#pragma unroll
        for (int kt = 0; kt < 2; ++kt) {
            whi[ft][kt].v = wf[((ft * 2 + kt) * 2 + 0) * 64 + lane];
            wlo[ft][kt].v = wf[((ft * 2 + kt) * 2 + 1) * 64 + lane];
        }
    }

    const float4* xr = (const float4*)in;
    size_t rbase = (size_t)node * 16 + (size_t)(kg * 2);
    int pnode = perm[node];
    size_t pbase = (size_t)pnode * 16 + (size_t)(kg * 2);
    f32x4 accP[4];
    f32x4 accN[4];
#pragma unroll
    for (int ft = 0; ft < 4; ++ft) {
        accP[ft] = f32x4{0.f, 0.f, 0.f, 0.f};
        accN[ft] = f32x4{0.f, 0.f, 0.f, 0.f};
    }
#pragma unroll
    for (int kt = 0; kt < 2; ++kt) {
        float4 a0 = xr[rbase + kt * 8];
        float4 a1 = xr[rbase + kt * 8 + 1];
        float4 g0 = xr[pbase + kt * 8];
        float4 g1 = xr[pbase + kt * 8 + 1];
        unsigned int h0, l0, h1, l1, h2, l2, h3, l3;
        split2(a0.x, a0.y, h0, l0);
        split2(a0.z, a0.w, h1, l1);
        split2(a1.x, a1.y, h2, l2);
        split2(a1.z, a1.w, h3, l3);
        FragU xhiP, xloP;
        xhiP.v = make_uint4(h0, h1, h2, h3);
        xloP.v = make_uint4(l0, l1, l2, l3);
        split2(g0.x, g0.y, h0, l0);
        split2(g0.z, g0.w, h1, l1);
        split2(g1.x, g1.y, h2, l2);
        split2(g1.z, g1.w, h3, l3);
        FragU xhiN, xloN;
        xhiN.v = make_uint4(h0, h1, h2, h3);
        xloN.v = make_uint4(l0, l1, l2, l3);
#pragma unroll
        for (int ft = 0; ft < 4; ++ft) {
            accP[ft] = __builtin_amdgcn_mfma_f32_16x16x32_bf16(whi[ft][kt].s, xhiP.s, accP[ft], 0, 0, 0);
            accP[ft] = __builtin_amdgcn_mfma_f32_16x16x32_bf16(whi[ft][kt].s, xloP.s, accP[ft], 0, 0, 0);
            accP[ft] = __builtin_amdgcn_mfma_f32_16x16x32_bf16(wlo[ft][kt].s, xhiP.s, accP[ft], 0, 0, 0);
            accN[ft] = __builtin_amdgcn_mfma_f32_16x16x32_bf16(whi[ft][kt].s, xhiN.s, accN[ft], 0, 0, 0);
            accN[ft] = __builtin_amdgcn_mfma_f32_16x16x32_bf16(whi[ft][kt].s, xloN.s, accN[ft], 0, 0, 0);
            accN[ft] = __builtin_amdgcn_mfma_f32_16x16x32_bf16(wlo[ft][kt].s, xhiN.s, accN[ft], 0, 0, 0);
        }
    }
    int fo = kg * 4;
    float s = dis[node];
    ushort_t* p = tPN + (size_t)node * 128;
#pragma unroll
    for (int ft = 0; ft < 4; ++ft) {
        uint2 up = make_uint2(packh(s * accP[ft][0], s * accP[ft][1]),
                              packh(s * accP[ft][2], s * accP[ft][3]));
        *(uint2*)(p + ft * 16 + fo) = up;
        uint2 un = make_uint2(packh(s * accN[ft][0], s * accN[ft][1]),
                              packh(s * accN[ft][2], s * accN[ft][3]));
        *(uint2*)(p + 64 + ft * 16 + fo) = un;
    }
}

// FUSED layer-1 aggregate + layer-2 GEMM. One block (4 waves) owns 16 rows.
// Phase 1 (gather, R2-proven structure): each wave aggregates 4 rows
// sequentially; lanes 0-31 = P half, 32-63 = N half, 2 feats/lane/4B-load;
// scols reads wave-uniform (scalar). H row (post bias+PReLU) parked in LDS
// [half][16][68] fp32. Phase 2 (MFMA): waves 0,1 -> P, waves 2,3 -> N;
// 2 ftiles/wave; same split2 hi/lo math as gemm1; epilogue scales by
// dis[row], writes fp16 table tOut (dense 8B stores).
__global__ void agg_gemm_k(const ushort_t* __restrict__ tIn, ushort_t* __restrict__ tOut,
                           const float* __restrict__ dis,
                           const int* __restrict__ rowstart, const int* __restrict__ deg,
                           const int* __restrict__ scols,
                           const float* __restrict__ bias, const float* __restrict__ prelu_a,
                           const uint4* __restrict__ wf) {
    __shared__ float Hs[2][16][68];
    int tid = threadIdx.x;
    int lane = tid & 63;
    int wv = tid >> 6;                 // 0..3
    int row0 = blockIdx.x * 16;
    int hl = lane & 31;
    int half = lane >> 5;
    size_t lofs = (size_t)(half * 64 + hl * 2);
    float aPr = *prelu_a;

    for (int rr = 0; rr < 4; ++rr) {
        int r = row0 + wv * 4 + rr;
        int rs   = __builtin_amdgcn_readfirstlane(r);
        int base = __builtin_amdgcn_readfirstlane(rowstart[rs]);
        int dg   = __builtin_amdgcn_readfirstlane(deg[rs]);
        float dr = dis[rs];
        unsigned int sv = *(const unsigned int*)(tIn + (size_t)rs * 128 + lofs);
        float2 fs = h2f(sv);
        float a0 = fs.x;
        float a1 = fs.y;     // self-loop term
        int j = 0;
        for (; j + 4 <= dg; j += 4) {
            int c0 = scols[base + j];
            int c1 = scols[base + j + 1];
            int c2 = scols[base + j + 2];
            int c3 = scols[base + j + 3];
            unsigned int v0 = *(const unsigned int*)(tIn + (size_t)c0 * 128 + lofs);
            unsigned int v1 = *(const unsigned int*)(tIn + (size_t)c1 * 128 + lofs);
            unsigned int v2 = *(const unsigned int*)(tIn + (size_t)c2 * 128 + lofs);
            unsigned int v3 = *(const unsigned int*)(tIn + (size_t)c3 * 128 + lofs);
            float2 f0 = h2f(v0);
            float2 f1 = h2f(v1);
            float2 f2 = h2f(v2);
            float2 f3 = h2f(v3);
            a0 += f0.x + f1.x + f2.x + f3.x;
            a1 += f0.y + f1.y + f2.y + f3.y;
        }
        for (; j < dg; ++j) {
            int c = scols[base + j];
            unsigned int v = *(const unsigned int*)(tIn + (size_t)c * 128 + lofs);
            float2 f = h2f(v);
            a0 += f.x;
            a1 += f.y;
        }
        float2 bv = *(const float2*)(bias + 2 * hl);
        float v0 = fmaf(dr, a0, bv.x);
        float v1 = fmaf(dr, a1, bv.y);
        v0 = v0 >= 0.f ? v0 : aPr * v0;
        v1 = v1 >= 0.f ? v1 : aPr * v1;
        int rl = wv * 4 + rr;
        Hs[half][rl][2 * hl]     = v0;
        Hs[half][rl][2 * hl + 1] = v1;
    }
    __syncthreads();

    // layer-2: out[row] = dis[row] * (H[row] @ W2), per half
    int kg = lane >> 4;
    int nd = lane & 15;
    int hsel = wv >> 1;                // waves 0,1 -> P; 2,3 -> N
    int ftb = (wv & 1) * 2;            // ftiles {0,1} or {2,3}
    FragU whi[2][2];
    FragU wlo[2][2];
#pragma unroll
    for (int f2 = 0; f2 < 2; ++f2) {
#pragma unroll
        for (int kt = 0; kt < 2; ++kt) {
            whi[f2][kt].v = wf[(((ftb + f2) * 2 + kt) * 2 + 0) * 64 + lane];
            wlo[f2][kt].v = wf[(((ftb + f2) * 2 + kt) * 2 + 1) * 64 + lane];
        }
    }
    f32x4 acc[2];
    acc[0] = f32x4{0.f, 0.f, 0.f, 0.f};
    acc[1] = f32x4{0.f, 0.f, 0.f, 0.f};
#pragma unroll
    for (int kt = 0; kt < 2; ++kt) {
        float4 a0 = *(const float4*)&Hs[hsel][nd][kt * 32 + kg * 8];
        float4 a1 = *(const float4*)&Hs[hsel][nd][kt * 32 + kg * 8 + 4];
        unsigned int h0, l0, h1, l1, h2, l2, h3, l3;
        split2(a0.x, a0.y, h0, l0);
        split2(a0.z, a0.w, h1, l1);
        split2(a1.x, a1.y, h2, l2);
        split2(a1.z, a1.w, h3, l3);
        FragU xhi, xlo;
        xhi.v = make_uint4(h0, h1, h2, h3);
        xlo.v = make_uint4(l0, l1, l2, l3);
#pragma unroll
        for (int f2 = 0; f2 < 2; ++f2) {
            acc[f2] = __builtin_amdgcn_mfma_f32_16x16x32_bf16(whi[f2][kt].s, xhi.s, acc[f2], 0, 0, 0);
            acc[f2] = __builtin_amdgcn_mfma_f32_16x16x32_bf16(whi[f2][kt].s, xlo.s, acc[f2], 0, 0, 0);
            acc[f2] = __builtin_amdgcn_mfma_f32_16x16x32_bf16(wlo[f2][kt].s, xhi.s, acc[f2], 0, 0, 0);
        }
    }
    float s = dis[row0 + nd];
    ushort_t* p = tOut + (size_t)(row0 + nd) * 128 + hsel * 64;
    int fo = kg * 4;
#pragma unroll
    for (int f2 = 0; f2 < 2; ++f2) {
        uint2 u = make_uint2(packh(s * acc[f2][0], s * acc[f2][1]),
                             packh(s * acc[f2][2], s * acc[f2][3]));
        *(uint2*)(p + (ftb + f2) * 16 + fo) = u;
    }
}

// Dual gather-aggregate over the interleaved fp16 table (final layer).
// One wave per row; lanes 0-31 = P half, 32-63 = N half; 2 feats/lane.
// outX[r] = dis[r]*(sum_j tX[c_j] + tX[r]) + b
__global__ void agg_dual_k(const ushort_t* __restrict__ tPN,
                           float* __restrict__ dstP, float* __restrict__ dstN,
                           const float* __restrict__ dis,
                           const int* __restrict__ rowstart, const int* __restrict__ deg,
                           const int* __restrict__ scols,
                           const float* __restrict__ bias, int n) {
    int lane = threadIdx.x & 63;
    int hl = lane & 31;
    int half = lane >> 5;
    int r = blockIdx.x * (blockDim.x >> 6) + (threadIdx.x >> 6);
    if (r >= n) return;
    int rs   = __builtin_amdgcn_readfirstlane(r);
    int base = __builtin_amdgcn_readfirstlane(rowstart[rs]);
    int dg   = __builtin_amdgcn_readfirstlane(deg[rs]);
    float dr = dis[rs];
    size_t lofs = (size_t)(half * 64 + hl * 2);
    unsigned int sv = *(const unsigned int*)(tPN + (size_t)rs * 128 + lofs);
    float2 fs = h2f(sv);
    float a0 = fs.x;
    float a1 = fs.y;     // self-loop term
    int j = 0;
    for (; j + 4 <= dg; j += 4) {
        int c0 = scols[base + j];
        int c1 = scols[base + j + 1];
        int c2 = scols[base + j + 2];
        int c3 = scols[base + j + 3];
        unsigned int v0 = *(const unsigned int*)(tPN + (size_t)c0 * 128 + lofs);
        unsigned int v1 = *(const unsigned int*)(tPN + (size_t)c1 * 128 + lofs);
        unsigned int v2 = *(const unsigned int*)(tPN + (size_t)c2 * 128 + lofs);
        unsigned int v3 = *(const unsigned int*)(tPN + (size_t)c3 * 128 + lofs);
        float2 f0 = h2f(v0);
        float2 f1 = h2f(v1);
        float2 f2 = h2f(v2);
        float2 f3 = h2f(v3);
        a0 += f0.x + f1.x + f2.x + f3.x;
        a1 += f0.y + f1.y + f2.y + f3.y;
    }
    for (; j < dg; ++j) {
        int c = scols[base + j];
        unsigned int v = *(const unsigned int*)(tPN + (size_t)c * 128 + lofs);
        float2 f = h2f(v);
        a0 += f.x;
        a1 += f.y;
    }
    float2 bv = *(const float2*)(bias + 2 * hl);
    float v0 = fmaf(dr, a0, bv.x);
    float v1 = fmaf(dr, a1, bv.y);
    float* dst = half ? dstN : dstP;
    *(float2*)(dst + (size_t)rs * D + 2 * hl) = float2{v0, v1};
}

// Summary partials: 512 blocks x 256 thr = 2048 waves, ~49 rows each.
// 4 independent accumulators keep 4 loads in flight (R8 lesson: a single
// `s += load` chain runs at 1 load / ~590 cyc -> 63us; ILP fixes it).
// One atomicAdd per wave-lane onto the 64-float acc (L2-resident, cheap).
__global__ void summary_partial_k(const float* __restrict__ pos, float* __restrict__ acc, int n) {
    int lane = threadIdx.x & 63;
    int wave = (blockIdx.x * blockDim.x + threadIdx.x) >> 6;
    int nw = (gridDim.x * blockDim.x) >> 6;
    float s0 = 0.f, s1 = 0.f, s2 = 0.f, s3 = 0.f;
    int r = wave;
    for (; r + 3 * nw < n; r += 4 * nw) {
        s0 += pos[(size_t)r * D + lane];
        s1 += pos[(size_t)(r + nw) * D + lane];
        s2 += pos[(size_t)(r + 2 * nw) * D + lane];
        s3 += pos[(size_t)(r + 3 * nw) * D + lane];
    }
    for (; r < n; r += nw) {
        s0 += pos[(size_t)r * D + lane];
    }
    atomicAdd(&acc[lane], (s0 + s1) + (s2 + s3));
}

__global__ void summary_final_k(const float* __restrict__ acc, float* __restrict__ out, int n) {
    int f = threadIdx.x;
    if (f < D) {
        float m = acc[f] / (float)n;
        out[f] = 1.f / (1.f + expf(-m));
    }
}

} // namespace

extern "C" void kernel_launch(void* const* d_in, const int* in_sizes, int n_in,
                              void* d_out, int out_size, void* d_ws, size_t ws_size,
                              hipStream_t stream) {
    (void)in_sizes; (void)n_in; (void)out_size; (void)ws_size;
    const float* x       = (const float*)d_in[0];
    const int*   ei      = (const int*)  d_in[1];
    const int*   perm    = (const int*)  d_in[2];
    const float* W1      = (const float*)d_in[3];
    const float* b1      = (const float*)d_in[4];
    const float* prelu_a = (const float*)d_in[5];
    const float* W2      = (const float*)d_in[6];
    const float* b2      = (const float*)d_in[7];

    float* outP = (float*)d_out;
    float* outN = outP + (size_t)NN * D;
    float* outS = outN + (size_t)NN * D;

    const int* erows = ei;
    const int* ecols = ei + NE;

    char* ws = (char*)d_ws;
    size_t off = 0;
    auto alloc = [&](size_t bytes) {
        void* p = ws + off;
        off = (off + bytes + 255) & ~(size_t)255;
        return p;
    };
    int*      deg      = (int*)     alloc((size_t)NN * 4);
    float*    dis      = (float*)   alloc((size_t)NN * 4);
    int*      rowstart = (int*)     alloc((size_t)NN * 4);
    int*      bcount   = (int*)     alloc((size_t)NBUK * 4);   // } one memset span
    float*    acc      = (float*)   alloc((size_t)D * 4);      // } (bcount..acc)
    unsigned int* binned = (unsigned int*)alloc((size_t)NBUK * CAP * 4);  // 6.4 MB
    int*      scols    = (int*)     alloc((size_t)NE * 4);
    ushort_t* tPN      = (ushort_t*)alloc((size_t)NN * 128 * 2);   // layer-1 fp16 table, 25.6 MB
    ushort_t* tPN2     = (ushort_t*)alloc((size_t)NN * 128 * 2);   // layer-2 fp16 table, 25.6 MB
    uint4*    wfrag    = (uint4*)   alloc((size_t)2 * 1024 * 16);  // W1|W2 bf16 hi/lo frags, 32 KB
    // ~65 MB total

    // one memset covers bcount (incl. alignment pad) + acc
    hipMemsetAsync(bcount, 0, (size_t)((char*)acc - (char*)bcount) + (size_t)D * 4, stream);

    // preprocessing: fused bin+wfrag -> per-bucket sort (scan in-block)
    binw_k<<<NTILES + 1, 256, 0, stream>>>(erows, ecols, bcount, binned, NE, W1, W2, wfrag);
    bucket_sort_k<<<NBUK, 512, 0, stream>>>(binned, bcount, scols, rowstart, deg, dis);

    // layer 1 GEMM: tPN[c] = [dis[c]*(x[c]@W1) | dis[c]*(x[perm[c]]@W1)]
    gemm1_k<<<(NN / 16 + 3) / 4, 256, 0, stream>>>(x, wfrag, tPN, perm, dis, NN);

    // fused layer-1 aggregate (+b1,PReLU) + layer-2 GEMM -> scaled fp16 table
    agg_gemm_k<<<NN / 16, 256, 0, stream>>>(tPN, tPN2, dis, rowstart, deg, scols,
                                            b1, prelu_a, wfrag + 1024);

    // final aggregate (+b2) -> outputs
    agg_dual_k<<<(NN + 3) / 4, 256, 0, stream>>>(tPN2, outP, outN, dis, rowstart, deg,
                                                 scols, b2, NN);

    // summary = sigmoid(mean(positive, axis=0))
    summary_partial_k<<<512, 256, 0, stream>>>(outP, acc, NN);
    summary_final_k<<<1, 64, 0, stream>>>(acc, outS, NN);
}

// Round 10
// 253.829 us; speedup vs baseline: 1.6383x; 1.1467x over previous
//
#include <hip/hip_runtime.h>
#include <hip/hip_fp16.h>
#include <math.h>

namespace {

constexpr int NN = 100000;   // nodes
constexpr int NE = 1000000;  // edges
constexpr int D  = 64;       // feature dim

constexpr int RPB_LOG = 8;                        // rows per bucket = 256
constexpr int RPB = 1 << RPB_LOG;
constexpr int NBUK = (NN + RPB - 1) >> RPB_LOG;   // 391 buckets
constexpr int CAP = 4096;                         // bucket capacity (mean 2558, +30 sigma)
constexpr int TILE = 2048;                        // edges per bin tile
constexpr int NTILES = (NE + TILE - 1) / TILE;    // 489

using ushort_t = unsigned short;
typedef __attribute__((ext_vector_type(8))) short short8;  // 8 bf16 (4 VGPRs)
typedef __attribute__((ext_vector_type(4))) float f32x4;   // MFMA 16x16 accumulator

union FragU { uint4 v; short8 s; };

// split two fp32 into packed bf16 hi parts and packed bf16 lo (residual) parts.
__device__ inline void split2(float f0, float f1, unsigned int& hi, unsigned int& lo) {
    unsigned int u0 = __float_as_uint(f0);
    unsigned int u1 = __float_as_uint(f1);
    hi = (u0 >> 16) | (u1 & 0xffff0000u);
    float l0 = f0 - __uint_as_float(u0 & 0xffff0000u);
    float l1 = f1 - __uint_as_float(u1 & 0xffff0000u);
    lo = (__float_as_uint(l0) >> 16) | (__float_as_uint(l1) & 0xffff0000u);
}

__device__ inline unsigned int packh(float a, float b) {   // 2x fp16 (RNE) packed
    union { __half2 h; unsigned int u; } cv;
    cv.h = __float22half2_rn(make_float2(a, b));
    return cv.u;
}

__device__ inline float2 h2f(unsigned int v) {
    union { unsigned int u; __half2 h; } cv;
    cv.u = v;
    return __half22float2(cv.h);
}

// Fused Phase A + weight-fragment precompute.
// Blocks [0, NTILES): bin edges into 391 fixed-capacity row-range buckets
// using LDS-local atomics + one global atomic per (block,bucket).
//   Payload packed: (r & 255) << 17 | c   (c < 2^17)
// Block NTILES: build MFMA A-operand fragments for W1|W2 (bf16 hi/lo),
//   layout per matrix: [ftile(4)][ktile(2)][hi/lo(2)][lane(64)] x 16B;
//   lane l holds A[m][k], m = ft*16 + (l&15), k = kt*32 + (l>>4)*8 + j.
// NOTE (R7 lesson): edge-scale DEVICE atomics / random 4B stores cost ~70us
// per pass on MI355X (cross-XCD coherence + 16x RFO amplification). Keep
// binning LDS-local with bucket-chunked payload writes.
__global__ void binw_k(const int* __restrict__ rows, const int* __restrict__ cols,
                       int* __restrict__ bcount, unsigned int* __restrict__ binned, int e,
                       const float* __restrict__ W1, const float* __restrict__ W2,
                       uint4* __restrict__ fb) {
    __shared__ int hist[NBUK];
    __shared__ int gbase[NBUK];
    __shared__ int lofs[NBUK];
    if (blockIdx.x == NTILES) {
        int lane = threadIdx.x;
        if (lane < 64) {
            for (int w = 0; w < 2; ++w) {
                const float* W = (w != 0) ? W2 : W1;
                uint4* out = fb + w * 1024;
                for (int ft = 0; ft < 4; ++ft) {
                    for (int kt = 0; kt < 2; ++kt) {
                        int m  = ft * 16 + (lane & 15);
                        int k0 = kt * 32 + (lane >> 4) * 8;
                        unsigned int hi0, lo0, hi1, lo1, hi2, lo2, hi3, lo3;
                        split2(W[(k0 + 0) * 64 + m], W[(k0 + 1) * 64 + m], hi0, lo0);
                        split2(W[(k0 + 2) * 64 + m], W[(k0 + 3) * 64 + m], hi1, lo1);
                        split2(W[(k0 + 4) * 64 + m], W[(k0 + 5) * 64 + m], hi2, lo2);
                        split2(W[(k0 + 6) * 64 + m], W[(k0 + 7) * 64 + m], hi3, lo3);
                        out[((ft * 2 + kt) * 2 + 0) * 64 + lane] = make_uint4(hi0, hi1, hi2, hi3);
                        out[((ft * 2 + kt) * 2 + 1) * 64 + lane] = make_uint4(lo0, lo1, lo2, lo3);
                    }
                }
            }
        }
        return;
    }
    int base = blockIdx.x * TILE;
    for (int i = threadIdx.x; i < NBUK; i += blockDim.x) {
        hist[i] = 0;
        lofs[i] = 0;
    }
    __syncthreads();
    int r[8];
    int c[8];
    int bk[8];
#pragma unroll
    for (int j = 0; j < 8; ++j) {
        int i = base + j * 256 + threadIdx.x;
        if (i < e) {
            r[j] = rows[i];
            c[j] = cols[i];
            bk[j] = r[j] >> RPB_LOG;
            atomicAdd(&hist[bk[j]], 1);
        } else {
            bk[j] = -1;
        }
    }
    __syncthreads();
    for (int b = threadIdx.x; b < NBUK; b += blockDim.x) {
        int h = hist[b];
        gbase[b] = h ? atomicAdd(&bcount[b], h) : 0;
    }
    __syncthreads();
#pragma unroll
    for (int j = 0; j < 8; ++j) {
        if (bk[j] >= 0) {
            int l = gbase[bk[j]] + atomicAdd(&lofs[bk[j]], 1);
            if (l < CAP) {
                unsigned int v = ((unsigned int)(r[j] & (RPB - 1)) << 17) | (unsigned int)c[j];
                binned[(size_t)bk[j] * CAP + l] = v;
            }
        }
    }
}

// Phase B: per-bucket counting sort + per-row deg/rowstart/dis production.
// Bucket base (exclusive scan of bcount over buckets < b) computed in-block.
__global__ void bucket_sort_k(const unsigned int* __restrict__ binned,
                              const int* __restrict__ bcount,
                              int* __restrict__ scols, int* __restrict__ rowstart,
                              int* __restrict__ deg, float* __restrict__ dis) {
    __shared__ int lcur[RPB];
    __shared__ int srs[RPB];
    __shared__ int wsum[8];
    __shared__ int redpart[8];
    __shared__ int sbase;
    int b = blockIdx.x;
    int row0 = b << RPB_LOG;
    int nrows = min(RPB, NN - row0);
    int cnt = bcount[b];
    const unsigned int* src = binned + (size_t)b * CAP;
    int tid = threadIdx.x;
    int lane = tid & 63;
    int wid = tid >> 6;

    // in-block exclusive bucket base: sum of bcount[i] for i < b
    int bv = (tid < NBUK && tid < b) ? bcount[tid] : 0;
    int bs = bv;
#pragma unroll
    for (int off = 1; off < 64; off <<= 1) {
        bs += __shfl_xor(bs, off, 64);
    }
    if (lane == 0) redpart[wid] = bs;
    __syncthreads();
    if (tid == 0) {
        int t = 0;
        for (int w = 0; w < 8; ++w) t += redpart[w];
        sbase = t;
    }
    if (tid < RPB) {
        lcur[tid] = 0;
    }
    __syncthreads();
    int bb = sbase;

    for (int i = tid; i < cnt; i += blockDim.x) {
        atomicAdd(&lcur[src[i] >> 17], 1);
    }
    __syncthreads();
    int d = (tid < nrows) ? lcur[tid] : 0;
    int inc = d;
#pragma unroll
    for (int off = 1; off < 64; off <<= 1) {
        int t = __shfl_up(inc, off);
        if (lane >= off) inc += t;
    }
    if (lane == 63) wsum[wid] = inc;
    __syncthreads();
    int wpre = 0;
    for (int w = 0; w < wid; ++w) wpre += wsum[w];
    int gstart = bb + wpre + inc - d;   // global exclusive prefix
    if (tid < nrows) {
        rowstart[row0 + tid] = gstart;
        deg[row0 + tid] = d;
        dis[row0 + tid] = rsqrtf((float)(d + 1));  // +1 self-loop
    }
    __syncthreads();
    if (tid < RPB) {
        srs[tid] = gstart;
        lcur[tid] = 0;
    }
    __syncthreads();
    for (int i = tid; i < cnt; i += blockDim.x) {
        unsigned int v = src[i];
        int rl = (int)(v >> 17);
        int pos = srs[rl] + atomicAdd(&lcur[rl], 1);
        scols[pos] = (int)(v & 0x1FFFFu);
    }
}

// Layer-1 MFMA GEMM: per output row c computes BOTH products
//   P[c] = dis[c]*(x[c]@W1),  N[c] = dis[c]*(x[perm[c]]@W1)
// via mfma_f32_16x16x32_bf16 with bf16 hi/lo split (~fp32 accuracy).
// One wave per 16-row tile; dense 256B interleaved-row writes (no scatter).
__global__ void gemm1_k(const float* __restrict__ in, const uint4* __restrict__ wf,
                        ushort_t* __restrict__ tPN, const int* __restrict__ perm,
                        const float* __restrict__ dis, int n) {
    int lane  = threadIdx.x & 63;
    int wtile = (int)((blockIdx.x * blockDim.x + threadIdx.x) >> 6);
    if (wtile * 16 >= n) return;
    int node = wtile * 16 + (lane & 15);
    int kg   = lane >> 4;  // 0..3

    FragU whi[4][2];
    FragU wlo[4][2];
#pragma unroll
    for (int ft = 0; ft < 4; ++ft) {
#pragma unroll
        for (int kt = 0; kt < 2; ++kt) {
            whi[ft][kt].v = wf[((ft * 2 + kt) * 2 + 0) * 64 + lane];
            wlo[ft][kt].v = wf[((ft * 2 + kt) * 2 + 1) * 64 + lane];
        }
    }

    const float4* xr = (const float4*)in;
    size_t rbase = (size_t)node * 16 + (size_t)(kg * 2);
    int pnode = perm[node];
    size_t pbase = (size_t)pnode * 16 + (size_t)(kg * 2);
    f32x4 accP[4];
    f32x4 accN[4];
#pragma unroll
    for (int ft = 0; ft < 4; ++ft) {
        accP[ft] = f32x4{0.f, 0.f, 0.f, 0.f};
        accN[ft] = f32x4{0.f, 0.f, 0.f, 0.f};
    }
#pragma unroll
    for (int kt = 0; kt < 2; ++kt) {
        float4 a0 = xr[rbase + kt * 8];
        float4 a1 = xr[rbase + kt * 8 + 1];
        float4 g0 = xr[pbase + kt * 8];
        float4 g1 = xr[pbase + kt * 8 + 1];
        unsigned int h0, l0, h1, l1, h2, l2, h3, l3;
        split2(a0.x, a0.y, h0, l0);
        split2(a0.z, a0.w, h1, l1);
        split2(a1.x, a1.y, h2, l2);
        split2(a1.z, a1.w, h3, l3);
        FragU xhiP, xloP;
        xhiP.v = make_uint4(h0, h1, h2, h3);
        xloP.v = make_uint4(l0, l1, l2, l3);
        split2(g0.x, g0.y, h0, l0);
        split2(g0.z, g0.w, h1, l1);
        split2(g1.x, g1.y, h2, l2);
        split2(g1.z, g1.w, h3, l3);
        FragU xhiN, xloN;
        xhiN.v = make_uint4(h0, h1, h2, h3);
        xloN.v = make_uint4(l0, l1, l2, l3);
#pragma unroll
        for (int ft = 0; ft < 4; ++ft) {
            accP[ft] = __builtin_amdgcn_mfma_f32_16x16x32_bf16(whi[ft][kt].s, xhiP.s, accP[ft], 0, 0, 0);
            accP[ft] = __builtin_amdgcn_mfma_f32_16x16x32_bf16(whi[ft][kt].s, xloP.s, accP[ft], 0, 0, 0);
            accP[ft] = __builtin_amdgcn_mfma_f32_16x16x32_bf16(wlo[ft][kt].s, xhiP.s, accP[ft], 0, 0, 0);
            accN[ft] = __builtin_amdgcn_mfma_f32_16x16x32_bf16(whi[ft][kt].s, xhiN.s, accN[ft], 0, 0, 0);
            accN[ft] = __builtin_amdgcn_mfma_f32_16x16x32_bf16(whi[ft][kt].s, xloN.s, accN[ft], 0, 0, 0);
            accN[ft] = __builtin_amdgcn_mfma_f32_16x16x32_bf16(wlo[ft][kt].s, xhiN.s, accN[ft], 0, 0, 0);
        }
    }
    int fo = kg * 4;
    float s = dis[node];
    ushort_t* p = tPN + (size_t)node * 128;
#pragma unroll
    for (int ft = 0; ft < 4; ++ft) {
        uint2 up = make_uint2(packh(s * accP[ft][0], s * accP[ft][1]),
                              packh(s * accP[ft][2], s * accP[ft][3]));
        *(uint2*)(p + ft * 16 + fo) = up;
        uint2 un = make_uint2(packh(s * accN[ft][0], s * accN[ft][1]),
                              packh(s * accN[ft][2], s * accN[ft][3]));
        *(uint2*)(p + 64 + ft * 16 + fo) = un;
    }
}

// FUSED layer-1 aggregate + layer-2 GEMM. One block (4 waves) owns 16 rows.
// Phase 1 (gather, R2-proven structure): each wave aggregates 4 rows
// sequentially; lanes 0-31 = P half, 32-63 = N half, 2 feats/lane/4B-load;
// scols reads wave-uniform (scalar). H row (post bias+PReLU) parked in LDS
// [half][16][68] fp32. Phase 2 (MFMA): waves 0,1 -> P, waves 2,3 -> N;
// 2 ftiles/wave; same split2 hi/lo math as gemm1; epilogue scales by
// dis[row], writes fp16 table tOut (dense 8B stores).
__global__ void agg_gemm_k(const ushort_t* __restrict__ tIn, ushort_t* __restrict__ tOut,
                           const float* __restrict__ dis,
                           const int* __restrict__ rowstart, const int* __restrict__ deg,
                           const int* __restrict__ scols,
                           const float* __restrict__ bias, const float* __restrict__ prelu_a,
                           const uint4* __restrict__ wf) {
    __shared__ float Hs[2][16][68];
    int tid = threadIdx.x;
    int lane = tid & 63;
    int wv = tid >> 6;                 // 0..3
    int row0 = blockIdx.x * 16;
    int hl = lane & 31;
    int half = lane >> 5;
    size_t lofs = (size_t)(half * 64 + hl * 2);
    float aPr = *prelu_a;

    for (int rr = 0; rr < 4; ++rr) {
        int r = row0 + wv * 4 + rr;
        int rs   = __builtin_amdgcn_readfirstlane(r);
        int base = __builtin_amdgcn_readfirstlane(rowstart[rs]);
        int dg   = __builtin_amdgcn_readfirstlane(deg[rs]);
        float dr = dis[rs];
        unsigned int sv = *(const unsigned int*)(tIn + (size_t)rs * 128 + lofs);
        float2 fs = h2f(sv);
        float a0 = fs.x;
        float a1 = fs.y;     // self-loop term
        int j = 0;
        for (; j + 4 <= dg; j += 4) {
            int c0 = scols[base + j];
            int c1 = scols[base + j + 1];
            int c2 = scols[base + j + 2];
            int c3 = scols[base + j + 3];
            unsigned int v0 = *(const unsigned int*)(tIn + (size_t)c0 * 128 + lofs);
            unsigned int v1 = *(const unsigned int*)(tIn + (size_t)c1 * 128 + lofs);
            unsigned int v2 = *(const unsigned int*)(tIn + (size_t)c2 * 128 + lofs);
            unsigned int v3 = *(const unsigned int*)(tIn + (size_t)c3 * 128 + lofs);
            float2 f0 = h2f(v0);
            float2 f1 = h2f(v1);
            float2 f2 = h2f(v2);
            float2 f3 = h2f(v3);
            a0 += f0.x + f1.x + f2.x + f3.x;
            a1 += f0.y + f1.y + f2.y + f3.y;
        }
        for (; j < dg; ++j) {
            int c = scols[base + j];
            unsigned int v = *(const unsigned int*)(tIn + (size_t)c * 128 + lofs);
            float2 f = h2f(v);
            a0 += f.x;
            a1 += f.y;
        }
        float2 bv = *(const float2*)(bias + 2 * hl);
        float v0 = fmaf(dr, a0, bv.x);
        float v1 = fmaf(dr, a1, bv.y);
        v0 = v0 >= 0.f ? v0 : aPr * v0;
        v1 = v1 >= 0.f ? v1 : aPr * v1;
        int rl = wv * 4 + rr;
        Hs[half][rl][2 * hl]     = v0;
        Hs[half][rl][2 * hl + 1] = v1;
    }
    __syncthreads();

    // layer-2: out[row] = dis[row] * (H[row] @ W2), per half
    int kg = lane >> 4;
    int nd = lane & 15;
    int hsel = wv >> 1;                // waves 0,1 -> P; 2,3 -> N
    int ftb = (wv & 1) * 2;            // ftiles {0,1} or {2,3}
    FragU whi[2][2];
    FragU wlo[2][2];
#pragma unroll
    for (int f2 = 0; f2 < 2; ++f2) {
#pragma unroll
        for (int kt = 0; kt < 2; ++kt) {
            whi[f2][kt].v = wf[(((ftb + f2) * 2 + kt) * 2 + 0) * 64 + lane];
            wlo[f2][kt].v = wf[(((ftb + f2) * 2 + kt) * 2 + 1) * 64 + lane];
        }
    }
    f32x4 acc[2];
    acc[0] = f32x4{0.f, 0.f, 0.f, 0.f};
    acc[1] = f32x4{0.f, 0.f, 0.f, 0.f};
#pragma unroll
    for (int kt = 0; kt < 2; ++kt) {
        float4 a0 = *(const float4*)&Hs[hsel][nd][kt * 32 + kg * 8];
        float4 a1 = *(const float4*)&Hs[hsel][nd][kt * 32 + kg * 8 + 4];
        unsigned int h0, l0, h1, l1, h2, l2, h3, l3;
        split2(a0.x, a0.y, h0, l0);
        split2(a0.z, a0.w, h1, l1);
        split2(a1.x, a1.y, h2, l2);
        split2(a1.z, a1.w, h3, l3);
        FragU xhi, xlo;
        xhi.v = make_uint4(h0, h1, h2, h3);
        xlo.v = make_uint4(l0, l1, l2, l3);
#pragma unroll
        for (int f2 = 0; f2 < 2; ++f2) {
            acc[f2] = __builtin_amdgcn_mfma_f32_16x16x32_bf16(whi[f2][kt].s, xhi.s, acc[f2], 0, 0, 0);
            acc[f2] = __builtin_amdgcn_mfma_f32_16x16x32_bf16(whi[f2][kt].s, xlo.s, acc[f2], 0, 0, 0);
            acc[f2] = __builtin_amdgcn_mfma_f32_16x16x32_bf16(wlo[f2][kt].s, xhi.s, acc[f2], 0, 0, 0);
        }
    }
    float s = dis[row0 + nd];
    ushort_t* p = tOut + (size_t)(row0 + nd) * 128 + hsel * 64;
    int fo = kg * 4;
#pragma unroll
    for (int f2 = 0; f2 < 2; ++f2) {
        uint2 u = make_uint2(packh(s * acc[f2][0], s * acc[f2][1]),
                             packh(s * acc[f2][2], s * acc[f2][3]));
        *(uint2*)(p + (ftb + f2) * 16 + fo) = u;
    }
}

// Dual gather-aggregate over the interleaved fp16 table (final layer).
// One wave per row; lanes 0-31 = P half, 32-63 = N half; 2 feats/lane.
// outX[r] = dis[r]*(sum_j tX[c_j] + tX[r]) + b
__global__ void agg_dual_k(const ushort_t* __restrict__ tPN,
                           float* __restrict__ dstP, float* __restrict__ dstN,
                           const float* __restrict__ dis,
                           const int* __restrict__ rowstart, const int* __restrict__ deg,
                           const int* __restrict__ scols,
                           const float* __restrict__ bias, int n) {
    int lane = threadIdx.x & 63;
    int hl = lane & 31;
    int half = lane >> 5;
    int r = blockIdx.x * (blockDim.x >> 6) + (threadIdx.x >> 6);
    if (r >= n) return;
    int rs   = __builtin_amdgcn_readfirstlane(r);
    int base = __builtin_amdgcn_readfirstlane(rowstart[rs]);
    int dg   = __builtin_amdgcn_readfirstlane(deg[rs]);
    float dr = dis[rs];
    size_t lofs = (size_t)(half * 64 + hl * 2);
    unsigned int sv = *(const unsigned int*)(tPN + (size_t)rs * 128 + lofs);
    float2 fs = h2f(sv);
    float a0 = fs.x;
    float a1 = fs.y;     // self-loop term
    int j = 0;
    for (; j + 4 <= dg; j += 4) {
        int c0 = scols[base + j];
        int c1 = scols[base + j + 1];
        int c2 = scols[base + j + 2];
        int c3 = scols[base + j + 3];
        unsigned int v0 = *(const unsigned int*)(tPN + (size_t)c0 * 128 + lofs);
        unsigned int v1 = *(const unsigned int*)(tPN + (size_t)c1 * 128 + lofs);
        unsigned int v2 = *(const unsigned int*)(tPN + (size_t)c2 * 128 + lofs);
        unsigned int v3 = *(const unsigned int*)(tPN + (size_t)c3 * 128 + lofs);
        float2 f0 = h2f(v0);
        float2 f1 = h2f(v1);
        float2 f2 = h2f(v2);
        float2 f3 = h2f(v3);
        a0 += f0.x + f1.x + f2.x + f3.x;
        a1 += f0.y + f1.y + f2.y + f3.y;
    }
    for (; j < dg; ++j) {
        int c = scols[base + j];
        unsigned int v = *(const unsigned int*)(tPN + (size_t)c * 128 + lofs);
        float2 f = h2f(v);
        a0 += f.x;
        a1 += f.y;
    }
    float2 bv = *(const float2*)(bias + 2 * hl);
    float v0 = fmaf(dr, a0, bv.x);
    float v1 = fmaf(dr, a1, bv.y);
    float* dst = half ? dstN : dstP;
    *(float2*)(dst + (size_t)rs * D + 2 * hl) = float2{v0, v1};
}

// Summary partials: 512 blocks x 256 thr. 4-acc ILP on the loads (R8 lesson:
// serial `s += load` = 1 load/~590cy). Per-block LDS reduce -> ONE 64-lane
// atomicAdd per BLOCK (R9 lesson: 2048 wave-atomics on the same 4 cache
// lines serialize at the cross-XCD far point, ~4cy each = 55us; 512 block
// atomics = ~1us).
__global__ void summary_partial_k(const float* __restrict__ pos, float* __restrict__ acc, int n) {
    __shared__ float red[4][64];
    int lane = threadIdx.x & 63;
    int wv = threadIdx.x >> 6;
    int wave = (blockIdx.x * blockDim.x + threadIdx.x) >> 6;
    int nw = (gridDim.x * blockDim.x) >> 6;
    float s0 = 0.f, s1 = 0.f, s2 = 0.f, s3 = 0.f;
    int r = wave;
    for (; r + 3 * nw < n; r += 4 * nw) {
        s0 += pos[(size_t)r * D + lane];
        s1 += pos[(size_t)(r + nw) * D + lane];
        s2 += pos[(size_t)(r + 2 * nw) * D + lane];
        s3 += pos[(size_t)(r + 3 * nw) * D + lane];
    }
    for (; r < n; r += nw) {
        s0 += pos[(size_t)r * D + lane];
    }
    red[wv][lane] = (s0 + s1) + (s2 + s3);
    __syncthreads();
    if (wv == 0) {
        float t = (red[0][lane] + red[1][lane]) + (red[2][lane] + red[3][lane]);
        atomicAdd(&acc[lane], t);
    }
}

__global__ void summary_final_k(const float* __restrict__ acc, float* __restrict__ out, int n) {
    int f = threadIdx.x;
    if (f < D) {
        float m = acc[f] / (float)n;
        out[f] = 1.f / (1.f + expf(-m));
    }
}

} // namespace

extern "C" void kernel_launch(void* const* d_in, const int* in_sizes, int n_in,
                              void* d_out, int out_size, void* d_ws, size_t ws_size,
                              hipStream_t stream) {
    (void)in_sizes; (void)n_in; (void)out_size; (void)ws_size;
    const float* x       = (const float*)d_in[0];
    const int*   ei      = (const int*)  d_in[1];
    const int*   perm    = (const int*)  d_in[2];
    const float* W1      = (const float*)d_in[3];
    const float* b1      = (const float*)d_in[4];
    const float* prelu_a = (const float*)d_in[5];
    const float* W2      = (const float*)d_in[6];
    const float* b2      = (const float*)d_in[7];

    float* outP = (float*)d_out;
    float* outN = outP + (size_t)NN * D;
    float* outS = outN + (size_t)NN * D;

    const int* erows = ei;
    const int* ecols = ei + NE;

    char* ws = (char*)d_ws;
    size_t off = 0;
    auto alloc = [&](size_t bytes) {
        void* p = ws + off;
        off = (off + bytes + 255) & ~(size_t)255;
        return p;
    };
    int*      deg      = (int*)     alloc((size_t)NN * 4);
    float*    dis      = (float*)   alloc((size_t)NN * 4);
    int*      rowstart = (int*)     alloc((size_t)NN * 4);
    int*      bcount   = (int*)     alloc((size_t)NBUK * 4);   // } one memset span
    float*    acc      = (float*)   alloc((size_t)D * 4);      // } (bcount..acc)
    unsigned int* binned = (unsigned int*)alloc((size_t)NBUK * CAP * 4);  // 6.4 MB
    int*      scols    = (int*)     alloc((size_t)NE * 4);
    ushort_t* tPN      = (ushort_t*)alloc((size_t)NN * 128 * 2);   // layer-1 fp16 table, 25.6 MB
    ushort_t* tPN2     = (ushort_t*)alloc((size_t)NN * 128 * 2);   // layer-2 fp16 table, 25.6 MB
    uint4*    wfrag    = (uint4*)   alloc((size_t)2 * 1024 * 16);  // W1|W2 bf16 hi/lo frags, 32 KB
    // ~65 MB total

    // one memset covers bcount (incl. alignment pad) + acc
    hipMemsetAsync(bcount, 0, (size_t)((char*)acc - (char*)bcount) + (size_t)D * 4, stream);

    // preprocessing: fused bin+wfrag -> per-bucket sort (scan in-block)
    binw_k<<<NTILES + 1, 256, 0, stream>>>(erows, ecols, bcount, binned, NE, W1, W2, wfrag);
    bucket_sort_k<<<NBUK, 512, 0, stream>>>(binned, bcount, scols, rowstart, deg, dis);

    // layer 1 GEMM: tPN[c] = [dis[c]*(x[c]@W1) | dis[c]*(x[perm[c]]@W1)]
    gemm1_k<<<(NN / 16 + 3) / 4, 256, 0, stream>>>(x, wfrag, tPN, perm, dis, NN);

    // fused layer-1 aggregate (+b1,PReLU) + layer-2 GEMM -> scaled fp16 table
    agg_gemm_k<<<NN / 16, 256, 0, stream>>>(tPN, tPN2, dis, rowstart, deg, scols,
                                            b1, prelu_a, wfrag + 1024);

    // final aggregate (+b2) -> outputs
    agg_dual_k<<<(NN + 3) / 4, 256, 0, stream>>>(tPN2, outP, outN, dis, rowstart, deg,
                                                 scols, b2, NN);

    // summary = sigmoid(mean(positive, axis=0))
    summary_partial_k<<<512, 256, 0, stream>>>(outP, acc, NN);
    summary_final_k<<<1, 64, 0, stream>>>(acc, outS, NN);
}